// Round 11
// baseline (453.251 us; speedup 1.0000x reference)
//
#include <hip/hip_runtime.h>
#include <cstdint>

typedef unsigned short u16;
typedef _Float16 half4v __attribute__((ext_vector_type(4)));
typedef float f32x4 __attribute__((ext_vector_type(4)));

#define AVG_LOG_F 1.4862356961977451f
#define MAXD 64

// ---- workspace float-unit offsets (weights region) ----
#define OFF_W2   3072   // pre_w2  fp32 [4][16][16]
#define OFF_PW1  4096   // post_w1 fp32 [4][256][16]
#define OFF_PW2  20480  // post_w2 fp32 [4][16][16]
#define OFF_LW   21504  // lin_w   fp32 [64][64]
#define OFF_PB1  25600
#define OFF_PB2  25664
#define OFF_QB1  25728
#define OFF_QB2  25792
#define OFF_LB   25856
#define OFF_LG   25920
#define OFF_LBN  25984
#define OFF_EWT  26128  // eWtab  fp32 [5][64]  (pb1 + ET.W1e, node-invariant)
#define IB       26448  // int region start (4B units)

__device__ __forceinline__ float bf2f(u16 u) {
    return __uint_as_float(((unsigned)u) << 16);
}
__device__ __forceinline__ u16 f2bf(float f) {
    unsigned u = __float_as_uint(f);
    u += 0x7fffu + ((u >> 16) & 1u);
    return (u16)(u >> 16);
}
__device__ __forceinline__ float rdin(const void* p, long j, int mode) {
    if (mode == 0) return bf2f(((const u16*)p)[j]);
    return ((const float*)p)[j];
}
template <int MODE>
__device__ __forceinline__ void load16c(const void* p, long base, float* o) {
    if (MODE == 0) {
        const u16* q = (const u16*)p + base;
        uint4 a = *(const uint4*)q;
        uint4 b = *(const uint4*)(q + 8);
        o[0]  = __uint_as_float(a.x << 16); o[1]  = __uint_as_float(a.x & 0xffff0000u);
        o[2]  = __uint_as_float(a.y << 16); o[3]  = __uint_as_float(a.y & 0xffff0000u);
        o[4]  = __uint_as_float(a.z << 16); o[5]  = __uint_as_float(a.z & 0xffff0000u);
        o[6]  = __uint_as_float(a.w << 16); o[7]  = __uint_as_float(a.w & 0xffff0000u);
        o[8]  = __uint_as_float(b.x << 16); o[9]  = __uint_as_float(b.x & 0xffff0000u);
        o[10] = __uint_as_float(b.y << 16); o[11] = __uint_as_float(b.y & 0xffff0000u);
        o[12] = __uint_as_float(b.z << 16); o[13] = __uint_as_float(b.z & 0xffff0000u);
        o[14] = __uint_as_float(b.w << 16); o[15] = __uint_as_float(b.w & 0xffff0000u);
    } else {
        const float* q = (const float*)p + base;
        float4 a = *(const float4*)q;
        float4 b = *(const float4*)(q + 4);
        float4 c = *(const float4*)(q + 8);
        float4 d = *(const float4*)(q + 12);
        o[0]=a.x; o[1]=a.y; o[2]=a.z; o[3]=a.w;
        o[4]=b.x; o[5]=b.y; o[6]=b.z; o[7]=b.w;
        o[8]=c.x; o[9]=c.y; o[10]=c.z; o[11]=c.w;
        o[12]=d.x; o[13]=d.y; o[14]=d.z; o[15]=d.w;
    }
}

// per-node precompute: Y[n][l] = x[n].W1_xj column,  XW[n][l] = x[n].W1_xi column
template <int MODE>
__device__ __forceinline__ void y_loop(const void* ax, const void* pre_w1, float* wsY, float* wsXW,
                                       int Nn, int wave, int nwaves, int l) {
    const int t = l >> 4, g = l & 15;
    float wxi[16], wxj[16];
#pragma unroll
    for (int f = 0; f < 16; f++) {
        wxi[f] = rdin(pre_w1, t * 768 + f * 16 + g, MODE);
        wxj[f] = rdin(pre_w1, t * 768 + (16 + f) * 16 + g, MODE);
    }
    for (int n = wave; n < Nn; n += nwaves) {
        float xj[16];
        load16c<MODE>(ax, (long)n * 64 + t * 16, xj);
        float accY = 0.f, accX = 0.f;
#pragma unroll
        for (int f = 0; f < 16; f++) {
            accY = fmaf(xj[f], wxj[f], accY);
            accX = fmaf(xj[f], wxi[f], accX);
        }
        wsY[(long)n * 64 + l]  = accY;
        wsXW[(long)n * 64 + l] = accX;
    }
}

// ---------------- 1: fused prep: weights->fp32, ET/eWtab, Y/XW precompute, edge scatter ----
__global__ __launch_bounds__(256) void k_prep(
    const int* __restrict__ dstp, const int* __restrict__ srcp, const int* __restrict__ bondp,
    const void* bond_emb, const void* edge_w, const void* edge_b,
    const void* pre_w1, const void* pre_b1, const void* pre_w2, const void* pre_b2,
    const void* post_w1, const void* post_b1, const void* post_w2, const void* post_b2,
    const void* lin_w, const void* lin_b, const void* ln_g, const void* ln_b,
    const void* ax, float* wsf, float* wsY, float* wsXW,
    int* __restrict__ cnt, int* __restrict__ pk, int* modep,
    int Nn, int E, int NIB)
{
    int tid = threadIdx.x;
    if ((int)blockIdx.x >= NIB) {            // ---- scatter part ----
        int e = ((int)blockIdx.x - NIB) * 256 + tid;
        if (e < E) {
            int d = dstp[e];
            int pos = atomicAdd(&cnt[d], 1);
            // pack (src*64)<<3 | bond  ->  k_node row offset = (v>>3)+l, bond = v&7
            if (pos < MAXD) pk[d * MAXD + pos] = (srcp[e] << 9) | (bondp[e] & 7);
        }
        return;
    }
    // ---- init part ----
    __shared__ int csh;
    __shared__ float ET[80];
    if (tid == 0) csh = 0;
    __syncthreads();
    {
        unsigned v = ((const unsigned*)ax)[tid];
        unsigned lo = v & 0xffffu;
        int ee = (int)((lo >> 7) & 0xff);
        int isbf = (lo == 0u) || (ee >= 110 && ee <= 140);
        atomicAdd(&csh, isbf);
    }
    __syncthreads();
    int mode = (csh >= 192) ? 0 : 1;

    int b = (int)blockIdx.x;
    int gt = b * 256 + tid;
    int gs = NIB * 256;
    if (b == 0 && tid == 0) modep[0] = mode;

    for (int j = gt; j < 1024; j += gs)  wsf[OFF_W2 + j]  = rdin(pre_w2, j, mode);
    for (int j = gt; j < 16384; j += gs) wsf[OFF_PW1 + j] = rdin(post_w1, j, mode);
    for (int j = gt; j < 1024; j += gs)  wsf[OFF_PW2 + j] = rdin(post_w2, j, mode);
    for (int j = gt; j < 4096; j += gs)  wsf[OFF_LW + j]  = rdin(lin_w, j, mode);
    for (int j = gt; j < 64; j += gs) {
        wsf[OFF_PB1 + j] = rdin(pre_b1, j, mode);
        wsf[OFF_PB2 + j] = rdin(pre_b2, j, mode);
        wsf[OFF_QB1 + j] = rdin(post_b1, j, mode);
        wsf[OFF_QB2 + j] = rdin(post_b2, j, mode);
        wsf[OFF_LB + j]  = rdin(lin_b, j, mode);
        wsf[OFF_LG + j]  = rdin(ln_g, j, mode);
        wsf[OFF_LBN + j] = rdin(ln_b, j, mode);
    }
    if (b == 0) {
        if (tid < 80) {
            int bb = tid >> 4, f = tid & 15;
            float acc = rdin(edge_b, f, mode);
            for (int k = 0; k < 64; k++)
                acc = fmaf(rdin(bond_emb, bb * 64 + k, mode), rdin(edge_w, k * 16 + f, mode), acc);
            ET[tid] = acc;
        }
        __syncthreads();
        for (int j = tid; j < 320; j += 256) {
            int bb = j >> 6, ll = j & 63, tt = ll >> 4, gg = ll & 15;
            float acc = rdin(pre_b1, tt * 16 + gg, mode);
#pragma unroll
            for (int f = 0; f < 16; f++)
                acc = fmaf(ET[bb * 16 + f], rdin(pre_w1, tt * 768 + (32 + f) * 16 + gg, mode), acc);
            wsf[OFF_EWT + j] = acc;
        }
    }
    int wave = gt >> 6;
    int nwaves = gs >> 6;
    int l = tid & 63;
    if (mode == 0) y_loop<0>(ax, pre_w1, wsY, wsXW, Nn, wave, nwaves, l);
    else           y_loop<1>(ax, pre_w1, wsY, wsXW, Nn, wave, nwaves, l);
}

// ---------------- 2: fused node kernel: all matmuls on matrix pipe, LDS overlays ---------
// 16 nodes/block, R10 structure. LDS trimmed 34.3->25.9KB via overlays (outf over zws,
// p1h/p2h over aggh[0]/aggh[1] — per-wave col-disjoint pre-barrier) -> 6 blocks/CU.
// Per-node prologue loads (cnt/pk/XWp/x_i) prefetched for all 4 wave-nodes up front.
__global__ __launch_bounds__(256, 6) void k_node(
    const void* __restrict__ ax, const float* __restrict__ Yp, const float* __restrict__ XWp,
    const int* __restrict__ pk, const int* __restrict__ cnt,
    const float* __restrict__ wsf, void* __restrict__ outp,
    const int* __restrict__ modep, int Nn)
{
    __shared__ _Float16 hbh[4][16][64];   // 8KB  per-wave edge-batch staging (swizzled)
    __shared__ float    zob[1280];        // 5KB  zws[4][5][64] (edge) ∪ outf[16][64] (final)
    __shared__ _Float16 xih[16][64];      // 2KB  x_i f16, swizzled rows
    __shared__ _Float16 aggh[5][16][64];  // 10KB stats f16; aggh[0]≡p1h, aggh[1]≡p2h overlay
    __shared__ float    scl1s[16], scl2s[16];

    const int w = threadIdx.x >> 6;
    const int l = threadIdx.x & 63;
    const int mode = modep[0];

    float* zws = &zob[w * 320];                        // [5][64] this wave (edge phase)
    float (*outf)[64] = (float(*)[64])&zob[0];         // [16][64] (after 2nd barrier)
    _Float16 (*p1h)[64] = (_Float16(*)[64])&aggh[0][0][0];
    _Float16 (*p2h)[64] = (_Float16(*)[64])&aggh[1][0][0];

    const int col  = l & 15;            // MFMA col / B col
    const int krow = (l >> 4) << 2;     // MFMA k-base / D row-base

    // ---- W2 B fragments + pb2 C-init for the edge-phase MFMAs ----
    half4v bfr[4];
    f32x4 cinit[4];
#pragma unroll
    for (int tt = 0; tt < 4; tt++) {
        half4v bv;
#pragma unroll
        for (int i = 0; i < 4; i++)
            bv[i] = (_Float16)wsf[OFF_W2 + tt * 256 + (krow + i) * 16 + col];
        bfr[tt] = bv;
        float pb = wsf[OFF_PB2 + tt * 16 + col];
        cinit[tt] = (f32x4){pb, pb, pb, pb};
    }

    const _Float16* hrow = &hbh[w][col][0];
    const int eswz = (l & 7) << 3;

    // ---- prefetch all 4 wave-node prologues (overlapped latencies) ----
    int pkv4[4]; float XW4[4], xi4[4]; int deg4[4];
#pragma unroll
    for (int j = 0; j < 4; j++) {
        const int ng = blockIdx.x * 16 + w * 4 + j;
        const bool act = (ng < Nn);
        const int nn = act ? ng : 0;
        deg4[j] = act ? cnt[nn] : 0;
        pkv4[j] = pk[nn * MAXD + l];
        XW4[j]  = XWp[(long)nn * 64 + l];
        xi4[j]  = rdin(ax, (long)nn * 64 + l, mode);
    }

    // ================= edge phase: 4 nodes per wave, sequential =================
#pragma unroll
    for (int j = 0; j < 4; j++) {
        const int ndl = w * 4 + j;
        int deg = deg4[j];
        if (deg > MAXD) deg = MAXD;
        const int pkv = pkv4[j];
        const float XWv = XW4[j];

        zws[0 * 64 + l] = XWv + wsf[OFF_EWT + 0 * 64 + l];
        zws[1 * 64 + l] = XWv + wsf[OFF_EWT + 1 * 64 + l];
        zws[2 * 64 + l] = XWv + wsf[OFF_EWT + 2 * 64 + l];
        zws[3 * 64 + l] = XWv + wsf[OFF_EWT + 3 * 64 + l];
        zws[4 * 64 + l] = XWv + wsf[OFF_EWT + 4 * 64 + l];
        const int nsw = (ndl & 7) << 3;
        xih[ndl][l ^ nsw] = (_Float16)xi4[j];

        float sA[4]  = {0.f, 0.f, 0.f, 0.f};
        float s2A[4] = {0.f, 0.f, 0.f, 0.f};
        float mnA[4] = {3.0e38f, 3.0e38f, 3.0e38f, 3.0e38f};
        float mxA[4] = {-3.0e38f, -3.0e38f, -3.0e38f, -3.0e38f};

        for (int kb = 0; kb < deg; kb += 16) {
            int B = deg - kb; if (B > 16) B = 16;
            int vs[16]; float yv[16];
#pragma unroll
            for (int k = 0; k < 16; k++) {
                if (k < B) {
                    vs[k] = __builtin_amdgcn_readlane(pkv, kb + k);
                    yv[k] = Yp[(vs[k] >> 3) + l];
                }
            }
#pragma unroll
            for (int k = 0; k < 16; k++) {
                float hv = (k < B) ? fmaxf(yv[k] + zws[(vs[k] & 7) * 64 + l], 0.f) : 0.f;
                hbh[w][k][l ^ ((k & 7) << 3)] = (_Float16)hv;
            }
            if (B == 16) {
#pragma unroll
                for (int tt = 0; tt < 4; tt++) {
                    half4v a = *(const half4v*)&hrow[(tt * 16 + krow) ^ eswz];
                    f32x4 d = __builtin_amdgcn_mfma_f32_16x16x16f16(a, bfr[tt], cinit[tt], 0, 0, 0);
#pragma unroll
                    for (int i = 0; i < 4; i++) {
                        float m = d[i];
                        sA[tt] += m;
                        s2A[tt] = fmaf(m, m, s2A[tt]);
                        mnA[tt] = fminf(mnA[tt], m);
                        mxA[tt] = fmaxf(mxA[tt], m);
                    }
                }
            } else {
                const int ebase = kb + krow;
#pragma unroll
                for (int tt = 0; tt < 4; tt++) {
                    half4v a = *(const half4v*)&hrow[(tt * 16 + krow) ^ eswz];
                    f32x4 d = __builtin_amdgcn_mfma_f32_16x16x16f16(a, bfr[tt], cinit[tt], 0, 0, 0);
#pragma unroll
                    for (int i = 0; i < 4; i++) {
                        bool val = (ebase + i) < deg;
                        float m = d[i];
                        float mm = val ? m : 0.f;
                        sA[tt] += mm;
                        s2A[tt] = fmaf(mm, mm, s2A[tt]);
                        mnA[tt] = fminf(mnA[tt], val ? m : 3.0e38f);
                        mxA[tt] = fmaxf(mxA[tt], val ? m : -3.0e38f);
                    }
                }
            }
        }

        // reduce edge-row groups (lanes xor 16/32 share col), select own tower (t=l>>4)
#pragma unroll
        for (int tt = 0; tt < 4; tt++) {
            sA[tt]  += __shfl_xor(sA[tt], 16);  sA[tt]  += __shfl_xor(sA[tt], 32);
            s2A[tt] += __shfl_xor(s2A[tt], 16); s2A[tt] += __shfl_xor(s2A[tt], 32);
            mnA[tt] = fminf(mnA[tt], __shfl_xor(mnA[tt], 16));
            mnA[tt] = fminf(mnA[tt], __shfl_xor(mnA[tt], 32));
            mxA[tt] = fmaxf(mxA[tt], __shfl_xor(mxA[tt], 16));
            mxA[tt] = fmaxf(mxA[tt], __shfl_xor(mxA[tt], 32));
        }
        const int t = l >> 4;
        float s  = (t & 2) ? ((t & 1) ? sA[3]  : sA[2])  : ((t & 1) ? sA[1]  : sA[0]);
        float s2 = (t & 2) ? ((t & 1) ? s2A[3] : s2A[2]) : ((t & 1) ? s2A[1] : s2A[0]);
        float mn = (t & 2) ? ((t & 1) ? mnA[3] : mnA[2]) : ((t & 1) ? mnA[1] : mnA[0]);
        float mx = (t & 2) ? ((t & 1) ? mxA[3] : mxA[2]) : ((t & 1) ? mxA[1] : mxA[0]);

        if (deg == 0) { mn = 0.f; mx = 0.f; }
        float cf = (float)(deg > 0 ? deg : 1);
        float inv = 1.0f / cf;
        float mean = s * inv;
        float var = s2 * inv - mean * mean;
        float sd = sqrtf(fmaxf(var, 0.f) + 1e-5f);
        float ldv = logf(cf + 1.0f);

        aggh[0][ndl][l ^ nsw] = (_Float16)s;
        aggh[1][ndl][l ^ nsw] = (_Float16)mean;
        aggh[2][ndl][l ^ nsw] = (_Float16)mn;
        aggh[3][ndl][l ^ nsw] = (_Float16)mx;
        aggh[4][ndl][l ^ nsw] = (_Float16)sd;
        if (l == 0) {
            scl1s[ndl] = ldv * (1.0f / AVG_LOG_F);
            scl2s[ndl] = AVG_LOG_F / ldv;
        }
    }
    __syncthreads();

    // ================= layer 1: wave w = tower w, 16 MFMAs over K=256 ==========
    const int t = w;
    const float* PW1t = wsf + OFF_PW1 + t * 4096;
    const int anode = col;                 // A row = node
    const int asw   = (anode & 7) << 3;
    const int achan = t * 16 + krow;       // chan base within node row

    half4v b1[16];
#pragma unroll
    for (int jj = 0; jj < 16; jj++) {
        int rbase = (jj == 0) ? 0
                  : (jj <= 5)  ? 16  + (jj - 1)  * 16
                  : (jj <= 10) ? 96  + (jj - 6)  * 16
                  :              176 + (jj - 11) * 16;
        half4v bv;
#pragma unroll
        for (int i = 0; i < 4; i++)
            bv[i] = (_Float16)PW1t[(rbase + krow + i) * 16 + col];
        b1[jj] = bv;
    }

    f32x4 zero4 = (f32x4){0.f, 0.f, 0.f, 0.f};
    f32x4 q0, q1v, q2v;
    {
        half4v a = *(const half4v*)&xih[anode][achan ^ asw];
        q0 = __builtin_amdgcn_mfma_f32_16x16x16f16(a, b1[0], zero4, 0, 0, 0);
    }
#pragma unroll
    for (int a5 = 0; a5 < 5; a5++) {
        half4v a = *(const half4v*)&aggh[a5][anode][achan ^ asw];
        q0 = __builtin_amdgcn_mfma_f32_16x16x16f16(a, b1[1 + a5], q0, 0, 0, 0);
    }
    q1v = zero4; q2v = zero4;
#pragma unroll
    for (int a5 = 0; a5 < 5; a5++) {
        half4v a = *(const half4v*)&aggh[a5][anode][achan ^ asw];
        q1v = __builtin_amdgcn_mfma_f32_16x16x16f16(a, b1[6 + a5],  q1v, 0, 0, 0);
        q2v = __builtin_amdgcn_mfma_f32_16x16x16f16(a, b1[11 + a5], q2v, 0, 0, 0);
    }
    {
        float qb1v = wsf[OFF_QB1 + t * 16 + col];
#pragma unroll
        for (int i = 0; i < 4; i++) {
            int ndr = krow + i;            // D row = node
            float p1 = q0[i] + scl1s[ndr] * q1v[i] + scl2s[ndr] * q2v[i] + qb1v;
            p1 = fmaxf(p1, 0.f);
            p1h[ndr][(t * 16 + col) ^ ((ndr & 7) << 3)] = (_Float16)p1;
        }
    }
    // p1h (overlay aggh[0]) tower-t cols written AND read by wave t only -> no barrier

    // ================= layer 2: 1 MFMA per tower-wave ==========================
    {
        const float* PW2t = wsf + OFF_PW2 + t * 256;
        half4v b2;
#pragma unroll
        for (int i = 0; i < 4; i++)
            b2[i] = (_Float16)PW2t[(krow + i) * 16 + col];
        float qb2v = wsf[OFF_QB2 + t * 16 + col];
        f32x4 c2 = (f32x4){qb2v, qb2v, qb2v, qb2v};
        half4v a2 = *(const half4v*)&p1h[anode][achan ^ asw];
        f32x4 m2 = __builtin_amdgcn_mfma_f32_16x16x16f16(a2, b2, c2, 0, 0, 0);
#pragma unroll
        for (int i = 0; i < 4; i++) {
            int ndr = krow + i;
            p2h[ndr][(t * 16 + col) ^ ((ndr & 7) << 3)] = (_Float16)m2[i];
        }
    }
    __syncthreads();

    // ================= final 64x64 linear: wave w -> out cols [16w,16w+16) =====
    {
        const float* LWp = wsf + OFF_LW;
        half4v bl[4];
#pragma unroll
        for (int s4 = 0; s4 < 4; s4++) {
            half4v bv;
#pragma unroll
            for (int i = 0; i < 4; i++)
                bv[i] = (_Float16)LWp[(16 * s4 + krow + i) * 64 + 16 * w + col];
            bl[s4] = bv;
        }
        float lbv = wsf[OFF_LB + 16 * w + col];
        f32x4 acc = (f32x4){lbv, lbv, lbv, lbv};
#pragma unroll
        for (int s4 = 0; s4 < 4; s4++) {
            half4v a = *(const half4v*)&p2h[anode][(16 * s4 + krow) ^ asw];
            acc = __builtin_amdgcn_mfma_f32_16x16x16f16(a, bl[s4], acc, 0, 0, 0);
        }
        __syncthreads();   // zws fully dead; outf overlay now safe to write
#pragma unroll
        for (int i = 0; i < 4; i++) {
            int ndr = krow + i;
            outf[ndr][16 * w + col] = acc[i];
        }
    }
    __syncthreads();

    // ================= LayerNorm + ReLU + residual: 4 nodes per wave ===========
    for (int j = 0; j < 4; j++) {
        const int ndl = w * 4 + j;
        const int ng  = blockIdx.x * 16 + ndl;
        float a = outf[ndl][l];
        float s1 = a, sq = a * a;
#pragma unroll
        for (int o = 1; o < 64; o <<= 1) { s1 += __shfl_xor(s1, o); sq += __shfl_xor(sq, o); }
        float mu = s1 * (1.0f / 64.0f);
        float varl = sq * (1.0f / 64.0f) - mu * mu;
        float ln = (a - mu) * rsqrtf(varl + 1e-5f) * wsf[OFF_LG + l] + wsf[OFF_LBN + l];
        if (ng < Nn) {
            long idx = (long)ng * 64 + l;
            float res = rdin(ax, idx, mode) + fmaxf(ln, 0.f);
            if (mode == 0) ((u16*)outp)[idx] = f2bf(res);
            else           ((float*)outp)[idx] = res;
        }
    }
}

extern "C" void kernel_launch(void* const* d_in, const int* in_sizes, int n_in,
                              void* d_out, int out_size, void* d_ws, size_t ws_size,
                              hipStream_t stream) {
    const void* atom_x   = d_in[0];
    const void* bond_emb = d_in[1];
    const void* edge_w   = d_in[2];
    const void* edge_b   = d_in[3];
    const void* pre_w1   = d_in[4];
    const void* pre_b1   = d_in[5];
    const void* pre_w2   = d_in[6];
    const void* pre_b2   = d_in[7];
    const void* post_w1  = d_in[8];
    const void* post_b1  = d_in[9];
    const void* post_w2  = d_in[10];
    const void* post_b2  = d_in[11];
    const void* lin_w    = d_in[12];
    const void* lin_b    = d_in[13];
    const void* ln_g     = d_in[14];
    const void* ln_b     = d_in[15];
    const int* bond_x    = (const int*)d_in[16];
    const int* aei       = (const int*)d_in[17];

    int E  = in_sizes[16];
    int Nn = in_sizes[0] / 64;
    const int* srcp = aei;
    const int* dstp = aei + E;

    float* wsf = (float*)d_ws;
    int*   wsi = (int*)d_ws;

    size_t o = IB;
    int* modep = wsi + o; o += 16;
    int* cnt   = wsi + o; o += Nn;
    o = (o + 63) & ~(size_t)63;
    int* pk    = wsi + o; o += (size_t)Nn * MAXD;
    float* Yp  = (float*)(wsi + o); o += (size_t)Nn * 64;
    float* XWp = (float*)(wsi + o); o += (size_t)Nn * 64;
    // ws usage ~39 MB

    const int NIB  = 1600;
    const int SBLK = (E + 255) / 256;

    (void)hipMemsetAsync(cnt, 0, (size_t)Nn * sizeof(int), stream);
    k_prep<<<NIB + SBLK, 256, 0, stream>>>(dstp, srcp, bond_x,
                                           bond_emb, edge_w, edge_b,
                                           pre_w1, pre_b1, pre_w2, pre_b2,
                                           post_w1, post_b1, post_w2, post_b2,
                                           lin_w, lin_b, ln_g, ln_b,
                                           atom_x, wsf, Yp, XWp, cnt, pk, modep, Nn, E, NIB);
    dim3 gn((Nn + 15) / 16, 1, 1);
    k_node<<<gn, 256, 0, stream>>>(atom_x, Yp, XWp, pk, cnt, wsf, d_out, modep, Nn);
}

// Round 12
// 277.558 us; speedup vs baseline: 1.6330x; 1.6330x over previous
//
#include <hip/hip_runtime.h>
#include <cstdint>

typedef unsigned short u16;
typedef _Float16 half4v __attribute__((ext_vector_type(4)));
typedef float f32x4 __attribute__((ext_vector_type(4)));

#define AVG_LOG_F 1.4862356961977451f
#define MAXD 64

// ---- workspace float-unit offsets (weights region) ----
#define OFF_W2   3072   // pre_w2  fp32 [4][16][16]
#define OFF_PW1  4096   // post_w1 fp32 [4][256][16]
#define OFF_PW2  20480  // post_w2 fp32 [4][16][16]
#define OFF_LW   21504  // lin_w   fp32 [64][64]
#define OFF_PB1  25600
#define OFF_PB2  25664
#define OFF_QB1  25728
#define OFF_QB2  25792
#define OFF_LB   25856
#define OFF_LG   25920
#define OFF_LBN  25984
#define OFF_EWT  26128  // eWtab  fp32 [5][64]  (pb1 + ET.W1e, node-invariant)
#define IB       26448  // int region start (4B units)

__device__ __forceinline__ float bf2f(u16 u) {
    return __uint_as_float(((unsigned)u) << 16);
}
__device__ __forceinline__ u16 f2bf(float f) {
    unsigned u = __float_as_uint(f);
    u += 0x7fffu + ((u >> 16) & 1u);
    return (u16)(u >> 16);
}
__device__ __forceinline__ float rdin(const void* p, long j, int mode) {
    if (mode == 0) return bf2f(((const u16*)p)[j]);
    return ((const float*)p)[j];
}
template <int MODE>
__device__ __forceinline__ void load16c(const void* p, long base, float* o) {
    if (MODE == 0) {
        const u16* q = (const u16*)p + base;
        uint4 a = *(const uint4*)q;
        uint4 b = *(const uint4*)(q + 8);
        o[0]  = __uint_as_float(a.x << 16); o[1]  = __uint_as_float(a.x & 0xffff0000u);
        o[2]  = __uint_as_float(a.y << 16); o[3]  = __uint_as_float(a.y & 0xffff0000u);
        o[4]  = __uint_as_float(a.z << 16); o[5]  = __uint_as_float(a.z & 0xffff0000u);
        o[6]  = __uint_as_float(a.w << 16); o[7]  = __uint_as_float(a.w & 0xffff0000u);
        o[8]  = __uint_as_float(b.x << 16); o[9]  = __uint_as_float(b.x & 0xffff0000u);
        o[10] = __uint_as_float(b.y << 16); o[11] = __uint_as_float(b.y & 0xffff0000u);
        o[12] = __uint_as_float(b.z << 16); o[13] = __uint_as_float(b.z & 0xffff0000u);
        o[14] = __uint_as_float(b.w << 16); o[15] = __uint_as_float(b.w & 0xffff0000u);
    } else {
        const float* q = (const float*)p + base;
        float4 a = *(const float4*)q;
        float4 b = *(const float4*)(q + 4);
        float4 c = *(const float4*)(q + 8);
        float4 d = *(const float4*)(q + 12);
        o[0]=a.x; o[1]=a.y; o[2]=a.z; o[3]=a.w;
        o[4]=b.x; o[5]=b.y; o[6]=b.z; o[7]=b.w;
        o[8]=c.x; o[9]=c.y; o[10]=c.z; o[11]=c.w;
        o[12]=d.x; o[13]=d.y; o[14]=d.z; o[15]=d.w;
    }
}

// per-node precompute: Y[n][l] = x[n].W1_xj column,  XW[n][l] = x[n].W1_xi column
template <int MODE>
__device__ __forceinline__ void y_loop(const void* ax, const void* pre_w1, float* wsY, float* wsXW,
                                       int Nn, int wave, int nwaves, int l) {
    const int t = l >> 4, g = l & 15;
    float wxi[16], wxj[16];
#pragma unroll
    for (int f = 0; f < 16; f++) {
        wxi[f] = rdin(pre_w1, t * 768 + f * 16 + g, MODE);
        wxj[f] = rdin(pre_w1, t * 768 + (16 + f) * 16 + g, MODE);
    }
    for (int n = wave; n < Nn; n += nwaves) {
        float xj[16];
        load16c<MODE>(ax, (long)n * 64 + t * 16, xj);
        float accY = 0.f, accX = 0.f;
#pragma unroll
        for (int f = 0; f < 16; f++) {
            accY = fmaf(xj[f], wxj[f], accY);
            accX = fmaf(xj[f], wxi[f], accX);
        }
        wsY[(long)n * 64 + l]  = accY;
        wsXW[(long)n * 64 + l] = accX;
    }
}

// ---------------- 1: fused prep: weights->fp32, ET/eWtab, Y/XW precompute, edge scatter ----
__global__ __launch_bounds__(256) void k_prep(
    const int* __restrict__ dstp, const int* __restrict__ srcp, const int* __restrict__ bondp,
    const void* bond_emb, const void* edge_w, const void* edge_b,
    const void* pre_w1, const void* pre_b1, const void* pre_w2, const void* pre_b2,
    const void* post_w1, const void* post_b1, const void* post_w2, const void* post_b2,
    const void* lin_w, const void* lin_b, const void* ln_g, const void* ln_b,
    const void* ax, float* wsf, float* wsY, float* wsXW,
    int* __restrict__ cnt, int* __restrict__ pk, int* modep,
    int Nn, int E, int NIB)
{
    int tid = threadIdx.x;
    if ((int)blockIdx.x >= NIB) {            // ---- scatter part ----
        int e = ((int)blockIdx.x - NIB) * 256 + tid;
        if (e < E) {
            int d = dstp[e];
            int pos = atomicAdd(&cnt[d], 1);
            // pack (src*64)<<3 | bond  ->  k_node row offset = (v>>3)+l, bond = v&7
            if (pos < MAXD) pk[d * MAXD + pos] = (srcp[e] << 9) | (bondp[e] & 7);
        }
        return;
    }
    // ---- init part ----
    __shared__ int csh;
    __shared__ float ET[80];
    if (tid == 0) csh = 0;
    __syncthreads();
    {
        unsigned v = ((const unsigned*)ax)[tid];
        unsigned lo = v & 0xffffu;
        int ee = (int)((lo >> 7) & 0xff);
        int isbf = (lo == 0u) || (ee >= 110 && ee <= 140);
        atomicAdd(&csh, isbf);
    }
    __syncthreads();
    int mode = (csh >= 192) ? 0 : 1;

    int b = (int)blockIdx.x;
    int gt = b * 256 + tid;
    int gs = NIB * 256;
    if (b == 0 && tid == 0) modep[0] = mode;

    for (int j = gt; j < 1024; j += gs)  wsf[OFF_W2 + j]  = rdin(pre_w2, j, mode);
    for (int j = gt; j < 16384; j += gs) wsf[OFF_PW1 + j] = rdin(post_w1, j, mode);
    for (int j = gt; j < 1024; j += gs)  wsf[OFF_PW2 + j] = rdin(post_w2, j, mode);
    for (int j = gt; j < 4096; j += gs)  wsf[OFF_LW + j]  = rdin(lin_w, j, mode);
    for (int j = gt; j < 64; j += gs) {
        wsf[OFF_PB1 + j] = rdin(pre_b1, j, mode);
        wsf[OFF_PB2 + j] = rdin(pre_b2, j, mode);
        wsf[OFF_QB1 + j] = rdin(post_b1, j, mode);
        wsf[OFF_QB2 + j] = rdin(post_b2, j, mode);
        wsf[OFF_LB + j]  = rdin(lin_b, j, mode);
        wsf[OFF_LG + j]  = rdin(ln_g, j, mode);
        wsf[OFF_LBN + j] = rdin(ln_b, j, mode);
    }
    if (b == 0) {
        if (tid < 80) {
            int bb = tid >> 4, f = tid & 15;
            float acc = rdin(edge_b, f, mode);
            for (int k = 0; k < 64; k++)
                acc = fmaf(rdin(bond_emb, bb * 64 + k, mode), rdin(edge_w, k * 16 + f, mode), acc);
            ET[tid] = acc;
        }
        __syncthreads();
        for (int j = tid; j < 320; j += 256) {
            int bb = j >> 6, ll = j & 63, tt = ll >> 4, gg = ll & 15;
            float acc = rdin(pre_b1, tt * 16 + gg, mode);
#pragma unroll
            for (int f = 0; f < 16; f++)
                acc = fmaf(ET[bb * 16 + f], rdin(pre_w1, tt * 768 + (32 + f) * 16 + gg, mode), acc);
            wsf[OFF_EWT + j] = acc;
        }
    }
    int wave = gt >> 6;
    int nwaves = gs >> 6;
    int l = tid & 63;
    if (mode == 0) y_loop<0>(ax, pre_w1, wsY, wsXW, Nn, wave, nwaves, l);
    else           y_loop<1>(ax, pre_w1, wsY, wsXW, Nn, wave, nwaves, l);
}

// ---------------- 2: fused node kernel: all matmuls on matrix pipe, LDS overlays ---------
// 16 nodes/block, R10 structure + LDS overlays (outf over zws, p1h/p2h over aggh[0..1]).
// launch_bounds(256,4): R11's (256,6) capped VGPR at 40 -> 1GB scratch spill (WRITE_SIZE
// 47->490MB). With VGPR<=~84 and LDS 25.5KB, occupancy is ~5-6 blocks/CU spill-free.
__global__ __launch_bounds__(256, 4) void k_node(
    const void* __restrict__ ax, const float* __restrict__ Yp, const float* __restrict__ XWp,
    const int* __restrict__ pk, const int* __restrict__ cnt,
    const float* __restrict__ wsf, void* __restrict__ outp,
    const int* __restrict__ modep, int Nn)
{
    __shared__ _Float16 hbh[4][16][64];   // 8KB  per-wave edge-batch staging (swizzled)
    __shared__ float    zob[1280];        // 5KB  zws[4][5][64] (edge) ∪ outf[16][64] (final)
    __shared__ _Float16 xih[16][64];      // 2KB  x_i f16, swizzled rows
    __shared__ _Float16 aggh[5][16][64];  // 10KB stats f16; aggh[0]≡p1h, aggh[1]≡p2h overlay
    __shared__ float    scl1s[16], scl2s[16];

    const int w = threadIdx.x >> 6;
    const int l = threadIdx.x & 63;
    const int mode = modep[0];

    float* zws = &zob[w * 320];                        // [5][64] this wave (edge phase)
    float (*outf)[64] = (float(*)[64])&zob[0];         // [16][64] (after 2nd barrier)
    _Float16 (*p1h)[64] = (_Float16(*)[64])&aggh[0][0][0];
    _Float16 (*p2h)[64] = (_Float16(*)[64])&aggh[1][0][0];

    const int col  = l & 15;            // MFMA col / B col
    const int krow = (l >> 4) << 2;     // MFMA k-base / D row-base

    // ---- W2 B fragments + pb2 C-init for the edge-phase MFMAs ----
    half4v bfr[4];
    f32x4 cinit[4];
#pragma unroll
    for (int tt = 0; tt < 4; tt++) {
        half4v bv;
#pragma unroll
        for (int i = 0; i < 4; i++)
            bv[i] = (_Float16)wsf[OFF_W2 + tt * 256 + (krow + i) * 16 + col];
        bfr[tt] = bv;
        float pb = wsf[OFF_PB2 + tt * 16 + col];
        cinit[tt] = (f32x4){pb, pb, pb, pb};
    }

    const _Float16* hrow = &hbh[w][col][0];
    const int eswz = (l & 7) << 3;

    // ---- prefetch all 4 wave-node prologues (overlapped latencies) ----
    int pkv4[4]; float XW4[4], xi4[4]; int deg4[4];
#pragma unroll
    for (int j = 0; j < 4; j++) {
        const int ng = blockIdx.x * 16 + w * 4 + j;
        const bool act = (ng < Nn);
        const int nn = act ? ng : 0;
        deg4[j] = act ? cnt[nn] : 0;
        pkv4[j] = pk[nn * MAXD + l];
        XW4[j]  = XWp[(long)nn * 64 + l];
        xi4[j]  = rdin(ax, (long)nn * 64 + l, mode);
    }

    // ================= edge phase: 4 nodes per wave, sequential =================
#pragma unroll
    for (int j = 0; j < 4; j++) {
        const int ndl = w * 4 + j;
        int deg = deg4[j];
        if (deg > MAXD) deg = MAXD;
        const int pkv = pkv4[j];
        const float XWv = XW4[j];

        zws[0 * 64 + l] = XWv + wsf[OFF_EWT + 0 * 64 + l];
        zws[1 * 64 + l] = XWv + wsf[OFF_EWT + 1 * 64 + l];
        zws[2 * 64 + l] = XWv + wsf[OFF_EWT + 2 * 64 + l];
        zws[3 * 64 + l] = XWv + wsf[OFF_EWT + 3 * 64 + l];
        zws[4 * 64 + l] = XWv + wsf[OFF_EWT + 4 * 64 + l];
        const int nsw = (ndl & 7) << 3;
        xih[ndl][l ^ nsw] = (_Float16)xi4[j];

        float sA[4]  = {0.f, 0.f, 0.f, 0.f};
        float s2A[4] = {0.f, 0.f, 0.f, 0.f};
        float mnA[4] = {3.0e38f, 3.0e38f, 3.0e38f, 3.0e38f};
        float mxA[4] = {-3.0e38f, -3.0e38f, -3.0e38f, -3.0e38f};

        for (int kb = 0; kb < deg; kb += 16) {
            int B = deg - kb; if (B > 16) B = 16;
            int vs[16]; float yv[16];
#pragma unroll
            for (int k = 0; k < 16; k++) {
                if (k < B) {
                    vs[k] = __builtin_amdgcn_readlane(pkv, kb + k);
                    yv[k] = Yp[(vs[k] >> 3) + l];
                }
            }
#pragma unroll
            for (int k = 0; k < 16; k++) {
                float hv = (k < B) ? fmaxf(yv[k] + zws[(vs[k] & 7) * 64 + l], 0.f) : 0.f;
                hbh[w][k][l ^ ((k & 7) << 3)] = (_Float16)hv;
            }
            if (B == 16) {
#pragma unroll
                for (int tt = 0; tt < 4; tt++) {
                    half4v a = *(const half4v*)&hrow[(tt * 16 + krow) ^ eswz];
                    f32x4 d = __builtin_amdgcn_mfma_f32_16x16x16f16(a, bfr[tt], cinit[tt], 0, 0, 0);
#pragma unroll
                    for (int i = 0; i < 4; i++) {
                        float m = d[i];
                        sA[tt] += m;
                        s2A[tt] = fmaf(m, m, s2A[tt]);
                        mnA[tt] = fminf(mnA[tt], m);
                        mxA[tt] = fmaxf(mxA[tt], m);
                    }
                }
            } else {
                const int ebase = kb + krow;
#pragma unroll
                for (int tt = 0; tt < 4; tt++) {
                    half4v a = *(const half4v*)&hrow[(tt * 16 + krow) ^ eswz];
                    f32x4 d = __builtin_amdgcn_mfma_f32_16x16x16f16(a, bfr[tt], cinit[tt], 0, 0, 0);
#pragma unroll
                    for (int i = 0; i < 4; i++) {
                        bool val = (ebase + i) < deg;
                        float m = d[i];
                        float mm = val ? m : 0.f;
                        sA[tt] += mm;
                        s2A[tt] = fmaf(mm, mm, s2A[tt]);
                        mnA[tt] = fminf(mnA[tt], val ? m : 3.0e38f);
                        mxA[tt] = fmaxf(mxA[tt], val ? m : -3.0e38f);
                    }
                }
            }
        }

        // reduce edge-row groups (lanes xor 16/32 share col), select own tower (t=l>>4)
#pragma unroll
        for (int tt = 0; tt < 4; tt++) {
            sA[tt]  += __shfl_xor(sA[tt], 16);  sA[tt]  += __shfl_xor(sA[tt], 32);
            s2A[tt] += __shfl_xor(s2A[tt], 16); s2A[tt] += __shfl_xor(s2A[tt], 32);
            mnA[tt] = fminf(mnA[tt], __shfl_xor(mnA[tt], 16));
            mnA[tt] = fminf(mnA[tt], __shfl_xor(mnA[tt], 32));
            mxA[tt] = fmaxf(mxA[tt], __shfl_xor(mxA[tt], 16));
            mxA[tt] = fmaxf(mxA[tt], __shfl_xor(mxA[tt], 32));
        }
        const int t = l >> 4;
        float s  = (t & 2) ? ((t & 1) ? sA[3]  : sA[2])  : ((t & 1) ? sA[1]  : sA[0]);
        float s2 = (t & 2) ? ((t & 1) ? s2A[3] : s2A[2]) : ((t & 1) ? s2A[1] : s2A[0]);
        float mn = (t & 2) ? ((t & 1) ? mnA[3] : mnA[2]) : ((t & 1) ? mnA[1] : mnA[0]);
        float mx = (t & 2) ? ((t & 1) ? mxA[3] : mxA[2]) : ((t & 1) ? mxA[1] : mxA[0]);

        if (deg == 0) { mn = 0.f; mx = 0.f; }
        float cf = (float)(deg > 0 ? deg : 1);
        float inv = 1.0f / cf;
        float mean = s * inv;
        float var = s2 * inv - mean * mean;
        float sd = sqrtf(fmaxf(var, 0.f) + 1e-5f);
        float ldv = logf(cf + 1.0f);

        aggh[0][ndl][l ^ nsw] = (_Float16)s;
        aggh[1][ndl][l ^ nsw] = (_Float16)mean;
        aggh[2][ndl][l ^ nsw] = (_Float16)mn;
        aggh[3][ndl][l ^ nsw] = (_Float16)mx;
        aggh[4][ndl][l ^ nsw] = (_Float16)sd;
        if (l == 0) {
            scl1s[ndl] = ldv * (1.0f / AVG_LOG_F);
            scl2s[ndl] = AVG_LOG_F / ldv;
        }
    }
    __syncthreads();

    // ================= layer 1: wave w = tower w, 16 MFMAs over K=256 ==========
    const int t = w;
    const float* PW1t = wsf + OFF_PW1 + t * 4096;
    const int anode = col;                 // A row = node
    const int asw   = (anode & 7) << 3;
    const int achan = t * 16 + krow;       // chan base within node row

    half4v b1[16];
#pragma unroll
    for (int jj = 0; jj < 16; jj++) {
        int rbase = (jj == 0) ? 0
                  : (jj <= 5)  ? 16  + (jj - 1)  * 16
                  : (jj <= 10) ? 96  + (jj - 6)  * 16
                  :              176 + (jj - 11) * 16;
        half4v bv;
#pragma unroll
        for (int i = 0; i < 4; i++)
            bv[i] = (_Float16)PW1t[(rbase + krow + i) * 16 + col];
        b1[jj] = bv;
    }

    f32x4 zero4 = (f32x4){0.f, 0.f, 0.f, 0.f};
    f32x4 q0, q1v, q2v;
    {
        half4v a = *(const half4v*)&xih[anode][achan ^ asw];
        q0 = __builtin_amdgcn_mfma_f32_16x16x16f16(a, b1[0], zero4, 0, 0, 0);
    }
#pragma unroll
    for (int a5 = 0; a5 < 5; a5++) {
        half4v a = *(const half4v*)&aggh[a5][anode][achan ^ asw];
        q0 = __builtin_amdgcn_mfma_f32_16x16x16f16(a, b1[1 + a5], q0, 0, 0, 0);
    }
    q1v = zero4; q2v = zero4;
#pragma unroll
    for (int a5 = 0; a5 < 5; a5++) {
        half4v a = *(const half4v*)&aggh[a5][anode][achan ^ asw];
        q1v = __builtin_amdgcn_mfma_f32_16x16x16f16(a, b1[6 + a5],  q1v, 0, 0, 0);
        q2v = __builtin_amdgcn_mfma_f32_16x16x16f16(a, b1[11 + a5], q2v, 0, 0, 0);
    }
    {
        float qb1v = wsf[OFF_QB1 + t * 16 + col];
#pragma unroll
        for (int i = 0; i < 4; i++) {
            int ndr = krow + i;            // D row = node
            float p1 = q0[i] + scl1s[ndr] * q1v[i] + scl2s[ndr] * q2v[i] + qb1v;
            p1 = fmaxf(p1, 0.f);
            p1h[ndr][(t * 16 + col) ^ ((ndr & 7) << 3)] = (_Float16)p1;
        }
    }
    // p1h (overlay aggh[0]) tower-t cols written AND read by wave t only -> no barrier

    // ================= layer 2: 1 MFMA per tower-wave ==========================
    {
        const float* PW2t = wsf + OFF_PW2 + t * 256;
        half4v b2;
#pragma unroll
        for (int i = 0; i < 4; i++)
            b2[i] = (_Float16)PW2t[(krow + i) * 16 + col];
        float qb2v = wsf[OFF_QB2 + t * 16 + col];
        f32x4 c2 = (f32x4){qb2v, qb2v, qb2v, qb2v};
        half4v a2 = *(const half4v*)&p1h[anode][achan ^ asw];
        f32x4 m2 = __builtin_amdgcn_mfma_f32_16x16x16f16(a2, b2, c2, 0, 0, 0);
#pragma unroll
        for (int i = 0; i < 4; i++) {
            int ndr = krow + i;
            p2h[ndr][(t * 16 + col) ^ ((ndr & 7) << 3)] = (_Float16)m2[i];
        }
    }
    __syncthreads();

    // ================= final 64x64 linear: wave w -> out cols [16w,16w+16) =====
    {
        const float* LWp = wsf + OFF_LW;
        half4v bl[4];
#pragma unroll
        for (int s4 = 0; s4 < 4; s4++) {
            half4v bv;
#pragma unroll
            for (int i = 0; i < 4; i++)
                bv[i] = (_Float16)LWp[(16 * s4 + krow + i) * 64 + 16 * w + col];
            bl[s4] = bv;
        }
        float lbv = wsf[OFF_LB + 16 * w + col];
        f32x4 acc = (f32x4){lbv, lbv, lbv, lbv};
#pragma unroll
        for (int s4 = 0; s4 < 4; s4++) {
            half4v a = *(const half4v*)&p2h[anode][(16 * s4 + krow) ^ asw];
            acc = __builtin_amdgcn_mfma_f32_16x16x16f16(a, bl[s4], acc, 0, 0, 0);
        }
        __syncthreads();   // zws fully dead; outf overlay now safe to write
#pragma unroll
        for (int i = 0; i < 4; i++) {
            int ndr = krow + i;
            outf[ndr][16 * w + col] = acc[i];
        }
    }
    __syncthreads();

    // ================= LayerNorm + ReLU + residual: 4 nodes per wave ===========
    for (int j = 0; j < 4; j++) {
        const int ndl = w * 4 + j;
        const int ng  = blockIdx.x * 16 + ndl;
        float a = outf[ndl][l];
        float s1 = a, sq = a * a;
#pragma unroll
        for (int o = 1; o < 64; o <<= 1) { s1 += __shfl_xor(s1, o); sq += __shfl_xor(sq, o); }
        float mu = s1 * (1.0f / 64.0f);
        float varl = sq * (1.0f / 64.0f) - mu * mu;
        float ln = (a - mu) * rsqrtf(varl + 1e-5f) * wsf[OFF_LG + l] + wsf[OFF_LBN + l];
        if (ng < Nn) {
            long idx = (long)ng * 64 + l;
            float res = rdin(ax, idx, mode) + fmaxf(ln, 0.f);
            if (mode == 0) ((u16*)outp)[idx] = f2bf(res);
            else           ((float*)outp)[idx] = res;
        }
    }
}

extern "C" void kernel_launch(void* const* d_in, const int* in_sizes, int n_in,
                              void* d_out, int out_size, void* d_ws, size_t ws_size,
                              hipStream_t stream) {
    const void* atom_x   = d_in[0];
    const void* bond_emb = d_in[1];
    const void* edge_w   = d_in[2];
    const void* edge_b   = d_in[3];
    const void* pre_w1   = d_in[4];
    const void* pre_b1   = d_in[5];
    const void* pre_w2   = d_in[6];
    const void* pre_b2   = d_in[7];
    const void* post_w1  = d_in[8];
    const void* post_b1  = d_in[9];
    const void* post_w2  = d_in[10];
    const void* post_b2  = d_in[11];
    const void* lin_w    = d_in[12];
    const void* lin_b    = d_in[13];
    const void* ln_g     = d_in[14];
    const void* ln_b     = d_in[15];
    const int* bond_x    = (const int*)d_in[16];
    const int* aei       = (const int*)d_in[17];

    int E  = in_sizes[16];
    int Nn = in_sizes[0] / 64;
    const int* srcp = aei;
    const int* dstp = aei + E;

    float* wsf = (float*)d_ws;
    int*   wsi = (int*)d_ws;

    size_t o = IB;
    int* modep = wsi + o; o += 16;
    int* cnt   = wsi + o; o += Nn;
    o = (o + 63) & ~(size_t)63;
    int* pk    = wsi + o; o += (size_t)Nn * MAXD;
    float* Yp  = (float*)(wsi + o); o += (size_t)Nn * 64;
    float* XWp = (float*)(wsi + o); o += (size_t)Nn * 64;
    // ws usage ~39 MB

    const int NIB  = 1600;
    const int SBLK = (E + 255) / 256;

    (void)hipMemsetAsync(cnt, 0, (size_t)Nn * sizeof(int), stream);
    k_prep<<<NIB + SBLK, 256, 0, stream>>>(dstp, srcp, bond_x,
                                           bond_emb, edge_w, edge_b,
                                           pre_w1, pre_b1, pre_w2, pre_b2,
                                           post_w1, post_b1, post_w2, post_b2,
                                           lin_w, lin_b, ln_g, ln_b,
                                           atom_x, wsf, Yp, XWp, cnt, pk, modep, Nn, E, NIB);
    dim3 gn((Nn + 15) / 16, 1, 1);
    k_node<<<gn, 256, 0, stream>>>(atom_x, Yp, XWp, pk, cnt, wsf, d_out, modep, Nn);
}

// Round 13
// 269.210 us; speedup vs baseline: 1.6836x; 1.0310x over previous
//
#include <hip/hip_runtime.h>
#include <cstdint>

typedef unsigned short u16;
typedef _Float16 half4v __attribute__((ext_vector_type(4)));
typedef float f32x4 __attribute__((ext_vector_type(4)));

#define AVG_LOG_F 1.4862356961977451f
#define MAXD 64

// ---- workspace float-unit offsets (weights region) ----
#define OFF_W2   3072   // pre_w2  fp32 [4][16][16]
#define OFF_PW1  4096   // post_w1 fp32 [4][256][16]
#define OFF_PW2  20480  // post_w2 fp32 [4][16][16]
#define OFF_LW   21504  // lin_w   fp32 [64][64]
#define OFF_PB1  25600
#define OFF_PB2  25664
#define OFF_QB1  25728
#define OFF_QB2  25792
#define OFF_LB   25856
#define OFF_LG   25920
#define OFF_LBN  25984
#define OFF_EWT  26128  // eWtab  fp32 [5][64]  (pb1 + ET.W1e, node-invariant)
#define IB       26448  // int region start (4B units)

__device__ __forceinline__ float bf2f(u16 u) {
    return __uint_as_float(((unsigned)u) << 16);
}
__device__ __forceinline__ u16 f2bf(float f) {
    unsigned u = __float_as_uint(f);
    u += 0x7fffu + ((u >> 16) & 1u);
    return (u16)(u >> 16);
}
__device__ __forceinline__ float rdin(const void* p, long j, int mode) {
    if (mode == 0) return bf2f(((const u16*)p)[j]);
    return ((const float*)p)[j];
}
template <int MODE>
__device__ __forceinline__ void load16c(const void* p, long base, float* o) {
    if (MODE == 0) {
        const u16* q = (const u16*)p + base;
        uint4 a = *(const uint4*)q;
        uint4 b = *(const uint4*)(q + 8);
        o[0]  = __uint_as_float(a.x << 16); o[1]  = __uint_as_float(a.x & 0xffff0000u);
        o[2]  = __uint_as_float(a.y << 16); o[3]  = __uint_as_float(a.y & 0xffff0000u);
        o[4]  = __uint_as_float(a.z << 16); o[5]  = __uint_as_float(a.z & 0xffff0000u);
        o[6]  = __uint_as_float(a.w << 16); o[7]  = __uint_as_float(a.w & 0xffff0000u);
        o[8]  = __uint_as_float(b.x << 16); o[9]  = __uint_as_float(b.x & 0xffff0000u);
        o[10] = __uint_as_float(b.y << 16); o[11] = __uint_as_float(b.y & 0xffff0000u);
        o[12] = __uint_as_float(b.z << 16); o[13] = __uint_as_float(b.z & 0xffff0000u);
        o[14] = __uint_as_float(b.w << 16); o[15] = __uint_as_float(b.w & 0xffff0000u);
    } else {
        const float* q = (const float*)p + base;
        float4 a = *(const float4*)q;
        float4 b = *(const float4*)(q + 4);
        float4 c = *(const float4*)(q + 8);
        float4 d = *(const float4*)(q + 12);
        o[0]=a.x; o[1]=a.y; o[2]=a.z; o[3]=a.w;
        o[4]=b.x; o[5]=b.y; o[6]=b.z; o[7]=b.w;
        o[8]=c.x; o[9]=c.y; o[10]=c.z; o[11]=c.w;
        o[12]=d.x; o[13]=d.y; o[14]=d.z; o[15]=d.w;
    }
}

// per-node precompute: Y[n][l] = x[n].W1_xj column,  XW[n][l] = x[n].W1_xi column
template <int MODE>
__device__ __forceinline__ void y_loop(const void* ax, const void* pre_w1, float* wsY, float* wsXW,
                                       int Nn, int wave, int nwaves, int l) {
    const int t = l >> 4, g = l & 15;
    float wxi[16], wxj[16];
#pragma unroll
    for (int f = 0; f < 16; f++) {
        wxi[f] = rdin(pre_w1, t * 768 + f * 16 + g, MODE);
        wxj[f] = rdin(pre_w1, t * 768 + (16 + f) * 16 + g, MODE);
    }
    for (int n = wave; n < Nn; n += nwaves) {
        float xj[16];
        load16c<MODE>(ax, (long)n * 64 + t * 16, xj);
        float accY = 0.f, accX = 0.f;
#pragma unroll
        for (int f = 0; f < 16; f++) {
            accY = fmaf(xj[f], wxj[f], accY);
            accX = fmaf(xj[f], wxi[f], accX);
        }
        wsY[(long)n * 64 + l]  = accY;
        wsXW[(long)n * 64 + l] = accX;
    }
}

// ---------------- 1: fused prep: weights->fp32, ET/eWtab, Y/XW precompute, edge scatter ----
__global__ __launch_bounds__(256) void k_prep(
    const int* __restrict__ dstp, const int* __restrict__ srcp, const int* __restrict__ bondp,
    const void* bond_emb, const void* edge_w, const void* edge_b,
    const void* pre_w1, const void* pre_b1, const void* pre_w2, const void* pre_b2,
    const void* post_w1, const void* post_b1, const void* post_w2, const void* post_b2,
    const void* lin_w, const void* lin_b, const void* ln_g, const void* ln_b,
    const void* ax, float* wsf, float* wsY, float* wsXW,
    int* __restrict__ cnt, int* __restrict__ pk, int* modep,
    int Nn, int E, int NIB)
{
    int tid = threadIdx.x;
    if ((int)blockIdx.x >= NIB) {            // ---- scatter part ----
        int e = ((int)blockIdx.x - NIB) * 256 + tid;
        if (e < E) {
            int d = dstp[e];
            int pos = atomicAdd(&cnt[d], 1);
            // pack (src*64)<<3 | bond  ->  k_node row offset = (v>>3)+l, bond = v&7
            if (pos < MAXD) pk[d * MAXD + pos] = (srcp[e] << 9) | (bondp[e] & 7);
        }
        return;
    }
    // ---- init part ----
    __shared__ int csh;
    __shared__ float ET[80];
    if (tid == 0) csh = 0;
    __syncthreads();
    {
        unsigned v = ((const unsigned*)ax)[tid];
        unsigned lo = v & 0xffffu;
        int ee = (int)((lo >> 7) & 0xff);
        int isbf = (lo == 0u) || (ee >= 110 && ee <= 140);
        atomicAdd(&csh, isbf);
    }
    __syncthreads();
    int mode = (csh >= 192) ? 0 : 1;

    int b = (int)blockIdx.x;
    int gt = b * 256 + tid;
    int gs = NIB * 256;
    if (b == 0 && tid == 0) modep[0] = mode;

    for (int j = gt; j < 1024; j += gs)  wsf[OFF_W2 + j]  = rdin(pre_w2, j, mode);
    for (int j = gt; j < 16384; j += gs) wsf[OFF_PW1 + j] = rdin(post_w1, j, mode);
    for (int j = gt; j < 1024; j += gs)  wsf[OFF_PW2 + j] = rdin(post_w2, j, mode);
    for (int j = gt; j < 4096; j += gs)  wsf[OFF_LW + j]  = rdin(lin_w, j, mode);
    for (int j = gt; j < 64; j += gs) {
        wsf[OFF_PB1 + j] = rdin(pre_b1, j, mode);
        wsf[OFF_PB2 + j] = rdin(pre_b2, j, mode);
        wsf[OFF_QB1 + j] = rdin(post_b1, j, mode);
        wsf[OFF_QB2 + j] = rdin(post_b2, j, mode);
        wsf[OFF_LB + j]  = rdin(lin_b, j, mode);
        wsf[OFF_LG + j]  = rdin(ln_g, j, mode);
        wsf[OFF_LBN + j] = rdin(ln_b, j, mode);
    }
    if (b == 0) {
        if (tid < 80) {
            int bb = tid >> 4, f = tid & 15;
            float acc = rdin(edge_b, f, mode);
            for (int k = 0; k < 64; k++)
                acc = fmaf(rdin(bond_emb, bb * 64 + k, mode), rdin(edge_w, k * 16 + f, mode), acc);
            ET[tid] = acc;
        }
        __syncthreads();
        for (int j = tid; j < 320; j += 256) {
            int bb = j >> 6, ll = j & 63, tt = ll >> 4, gg = ll & 15;
            float acc = rdin(pre_b1, tt * 16 + gg, mode);
#pragma unroll
            for (int f = 0; f < 16; f++)
                acc = fmaf(ET[bb * 16 + f], rdin(pre_w1, tt * 768 + (32 + f) * 16 + gg, mode), acc);
            wsf[OFF_EWT + j] = acc;
        }
    }
    int wave = gt >> 6;
    int nwaves = gs >> 6;
    int l = tid & 63;
    if (mode == 0) y_loop<0>(ax, pre_w1, wsY, wsXW, Nn, wave, nwaves, l);
    else           y_loop<1>(ax, pre_w1, wsY, wsXW, Nn, wave, nwaves, l);
}

// ---------------- 2: fused node kernel: all matmuls on matrix pipe, LDS overlays ---------
// 16 nodes/block, R10 structure + LDS overlays. amdgpu_waves_per_eu(4,4): R10/R12 showed
// the allocator targets 8 waves/SIMD (64-reg step) and spills 35-75MB to scratch even
// though LDS caps blocks/CU at 4-6. Pinning max=4 waves/EU gives the full 128-VGPR
// budget -> zero spill (canary: WRITE_SIZE 122->13MB, VGPR_Count ~96-128).
__global__ __launch_bounds__(256) __attribute__((amdgpu_waves_per_eu(4, 4))) void k_node(
    const void* __restrict__ ax, const float* __restrict__ Yp, const float* __restrict__ XWp,
    const int* __restrict__ pk, const int* __restrict__ cnt,
    const float* __restrict__ wsf, void* __restrict__ outp,
    const int* __restrict__ modep, int Nn)
{
    __shared__ _Float16 hbh[4][16][64];   // 8KB  per-wave edge-batch staging (swizzled)
    __shared__ float    zob[1280];        // 5KB  zws[4][5][64] (edge) ∪ outf[16][64] (final)
    __shared__ _Float16 xih[16][64];      // 2KB  x_i f16, swizzled rows
    __shared__ _Float16 aggh[5][16][64];  // 10KB stats f16; aggh[0]≡p1h, aggh[1]≡p2h overlay
    __shared__ float    scl1s[16], scl2s[16];

    const int w = threadIdx.x >> 6;
    const int l = threadIdx.x & 63;
    const int mode = modep[0];

    float* zws = &zob[w * 320];                        // [5][64] this wave (edge phase)
    float (*outf)[64] = (float(*)[64])&zob[0];         // [16][64] (after 2nd barrier)
    _Float16 (*p1h)[64] = (_Float16(*)[64])&aggh[0][0][0];
    _Float16 (*p2h)[64] = (_Float16(*)[64])&aggh[1][0][0];

    const int col  = l & 15;            // MFMA col / B col
    const int krow = (l >> 4) << 2;     // MFMA k-base / D row-base

    // ---- W2 B fragments + pb2 C-init for the edge-phase MFMAs ----
    half4v bfr[4];
    f32x4 cinit[4];
#pragma unroll
    for (int tt = 0; tt < 4; tt++) {
        half4v bv;
#pragma unroll
        for (int i = 0; i < 4; i++)
            bv[i] = (_Float16)wsf[OFF_W2 + tt * 256 + (krow + i) * 16 + col];
        bfr[tt] = bv;
        float pb = wsf[OFF_PB2 + tt * 16 + col];
        cinit[tt] = (f32x4){pb, pb, pb, pb};
    }

    const _Float16* hrow = &hbh[w][col][0];
    const int eswz = (l & 7) << 3;

    // ================= edge phase: 4 nodes per wave, sequential =================
    for (int j = 0; j < 4; j++) {
        const int ndl = w * 4 + j;
        const int ng  = blockIdx.x * 16 + ndl;
        const bool act = (ng < Nn);
        const int nn = act ? ng : 0;
        int deg = act ? cnt[nn] : 0;
        if (deg > MAXD) deg = MAXD;

        int   pkv = pk[nn * MAXD + l];
        float XWv = XWp[(long)nn * 64 + l];
        zws[0 * 64 + l] = XWv + wsf[OFF_EWT + 0 * 64 + l];
        zws[1 * 64 + l] = XWv + wsf[OFF_EWT + 1 * 64 + l];
        zws[2 * 64 + l] = XWv + wsf[OFF_EWT + 2 * 64 + l];
        zws[3 * 64 + l] = XWv + wsf[OFF_EWT + 3 * 64 + l];
        zws[4 * 64 + l] = XWv + wsf[OFF_EWT + 4 * 64 + l];
        const int nsw = (ndl & 7) << 3;
        xih[ndl][l ^ nsw] = (_Float16)rdin(ax, (long)nn * 64 + l, mode);

        float sA[4]  = {0.f, 0.f, 0.f, 0.f};
        float s2A[4] = {0.f, 0.f, 0.f, 0.f};
        float mnA[4] = {3.0e38f, 3.0e38f, 3.0e38f, 3.0e38f};
        float mxA[4] = {-3.0e38f, -3.0e38f, -3.0e38f, -3.0e38f};

        for (int kb = 0; kb < deg; kb += 16) {
            int B = deg - kb; if (B > 16) B = 16;
            int vs[16]; float yv[16];
#pragma unroll
            for (int k = 0; k < 16; k++) {
                if (k < B) {
                    vs[k] = __builtin_amdgcn_readlane(pkv, kb + k);
                    yv[k] = Yp[(vs[k] >> 3) + l];
                }
            }
#pragma unroll
            for (int k = 0; k < 16; k++) {
                float hv = (k < B) ? fmaxf(yv[k] + zws[(vs[k] & 7) * 64 + l], 0.f) : 0.f;
                hbh[w][k][l ^ ((k & 7) << 3)] = (_Float16)hv;
            }
            if (B == 16) {
#pragma unroll
                for (int tt = 0; tt < 4; tt++) {
                    half4v a = *(const half4v*)&hrow[(tt * 16 + krow) ^ eswz];
                    f32x4 d = __builtin_amdgcn_mfma_f32_16x16x16f16(a, bfr[tt], cinit[tt], 0, 0, 0);
#pragma unroll
                    for (int i = 0; i < 4; i++) {
                        float m = d[i];
                        sA[tt] += m;
                        s2A[tt] = fmaf(m, m, s2A[tt]);
                        mnA[tt] = fminf(mnA[tt], m);
                        mxA[tt] = fmaxf(mxA[tt], m);
                    }
                }
            } else {
                const int ebase = kb + krow;
#pragma unroll
                for (int tt = 0; tt < 4; tt++) {
                    half4v a = *(const half4v*)&hrow[(tt * 16 + krow) ^ eswz];
                    f32x4 d = __builtin_amdgcn_mfma_f32_16x16x16f16(a, bfr[tt], cinit[tt], 0, 0, 0);
#pragma unroll
                    for (int i = 0; i < 4; i++) {
                        bool val = (ebase + i) < deg;
                        float m = d[i];
                        float mm = val ? m : 0.f;
                        sA[tt] += mm;
                        s2A[tt] = fmaf(mm, mm, s2A[tt]);
                        mnA[tt] = fminf(mnA[tt], val ? m : 3.0e38f);
                        mxA[tt] = fmaxf(mxA[tt], val ? m : -3.0e38f);
                    }
                }
            }
        }

        // reduce edge-row groups (lanes xor 16/32 share col), select own tower (t=l>>4)
#pragma unroll
        for (int tt = 0; tt < 4; tt++) {
            sA[tt]  += __shfl_xor(sA[tt], 16);  sA[tt]  += __shfl_xor(sA[tt], 32);
            s2A[tt] += __shfl_xor(s2A[tt], 16); s2A[tt] += __shfl_xor(s2A[tt], 32);
            mnA[tt] = fminf(mnA[tt], __shfl_xor(mnA[tt], 16));
            mnA[tt] = fminf(mnA[tt], __shfl_xor(mnA[tt], 32));
            mxA[tt] = fmaxf(mxA[tt], __shfl_xor(mxA[tt], 16));
            mxA[tt] = fmaxf(mxA[tt], __shfl_xor(mxA[tt], 32));
        }
        const int t = l >> 4;
        float s  = (t & 2) ? ((t & 1) ? sA[3]  : sA[2])  : ((t & 1) ? sA[1]  : sA[0]);
        float s2 = (t & 2) ? ((t & 1) ? s2A[3] : s2A[2]) : ((t & 1) ? s2A[1] : s2A[0]);
        float mn = (t & 2) ? ((t & 1) ? mnA[3] : mnA[2]) : ((t & 1) ? mnA[1] : mnA[0]);
        float mx = (t & 2) ? ((t & 1) ? mxA[3] : mxA[2]) : ((t & 1) ? mxA[1] : mxA[0]);

        if (deg == 0) { mn = 0.f; mx = 0.f; }
        float cf = (float)(deg > 0 ? deg : 1);
        float inv = 1.0f / cf;
        float mean = s * inv;
        float var = s2 * inv - mean * mean;
        float sd = sqrtf(fmaxf(var, 0.f) + 1e-5f);
        float ldv = logf(cf + 1.0f);

        aggh[0][ndl][l ^ nsw] = (_Float16)s;
        aggh[1][ndl][l ^ nsw] = (_Float16)mean;
        aggh[2][ndl][l ^ nsw] = (_Float16)mn;
        aggh[3][ndl][l ^ nsw] = (_Float16)mx;
        aggh[4][ndl][l ^ nsw] = (_Float16)sd;
        if (l == 0) {
            scl1s[ndl] = ldv * (1.0f / AVG_LOG_F);
            scl2s[ndl] = AVG_LOG_F / ldv;
        }
    }
    __syncthreads();

    // ================= layer 1: wave w = tower w, 16 MFMAs over K=256 ==========
    const int t = w;
    const float* PW1t = wsf + OFF_PW1 + t * 4096;
    const int anode = col;                 // A row = node
    const int asw   = (anode & 7) << 3;
    const int achan = t * 16 + krow;       // chan base within node row

    half4v b1[16];
#pragma unroll
    for (int jj = 0; jj < 16; jj++) {
        int rbase = (jj == 0) ? 0
                  : (jj <= 5)  ? 16  + (jj - 1)  * 16
                  : (jj <= 10) ? 96  + (jj - 6)  * 16
                  :              176 + (jj - 11) * 16;
        half4v bv;
#pragma unroll
        for (int i = 0; i < 4; i++)
            bv[i] = (_Float16)PW1t[(rbase + krow + i) * 16 + col];
        b1[jj] = bv;
    }

    f32x4 zero4 = (f32x4){0.f, 0.f, 0.f, 0.f};
    f32x4 q0, q1v, q2v;
    {
        half4v a = *(const half4v*)&xih[anode][achan ^ asw];
        q0 = __builtin_amdgcn_mfma_f32_16x16x16f16(a, b1[0], zero4, 0, 0, 0);
    }
#pragma unroll
    for (int a5 = 0; a5 < 5; a5++) {
        half4v a = *(const half4v*)&aggh[a5][anode][achan ^ asw];
        q0 = __builtin_amdgcn_mfma_f32_16x16x16f16(a, b1[1 + a5], q0, 0, 0, 0);
    }
    q1v = zero4; q2v = zero4;
#pragma unroll
    for (int a5 = 0; a5 < 5; a5++) {
        half4v a = *(const half4v*)&aggh[a5][anode][achan ^ asw];
        q1v = __builtin_amdgcn_mfma_f32_16x16x16f16(a, b1[6 + a5],  q1v, 0, 0, 0);
        q2v = __builtin_amdgcn_mfma_f32_16x16x16f16(a, b1[11 + a5], q2v, 0, 0, 0);
    }
    {
        float qb1v = wsf[OFF_QB1 + t * 16 + col];
#pragma unroll
        for (int i = 0; i < 4; i++) {
            int ndr = krow + i;            // D row = node
            float p1 = q0[i] + scl1s[ndr] * q1v[i] + scl2s[ndr] * q2v[i] + qb1v;
            p1 = fmaxf(p1, 0.f);
            p1h[ndr][(t * 16 + col) ^ ((ndr & 7) << 3)] = (_Float16)p1;
        }
    }
    // p1h (overlay aggh[0]) tower-t cols written AND read by wave t only -> no barrier

    // ================= layer 2: 1 MFMA per tower-wave ==========================
    {
        const float* PW2t = wsf + OFF_PW2 + t * 256;
        half4v b2;
#pragma unroll
        for (int i = 0; i < 4; i++)
            b2[i] = (_Float16)PW2t[(krow + i) * 16 + col];
        float qb2v = wsf[OFF_QB2 + t * 16 + col];
        f32x4 c2 = (f32x4){qb2v, qb2v, qb2v, qb2v};
        half4v a2 = *(const half4v*)&p1h[anode][achan ^ asw];
        f32x4 m2 = __builtin_amdgcn_mfma_f32_16x16x16f16(a2, b2, c2, 0, 0, 0);
#pragma unroll
        for (int i = 0; i < 4; i++) {
            int ndr = krow + i;
            p2h[ndr][(t * 16 + col) ^ ((ndr & 7) << 3)] = (_Float16)m2[i];
        }
    }
    __syncthreads();

    // ================= final 64x64 linear: wave w -> out cols [16w,16w+16) =====
    {
        const float* LWp = wsf + OFF_LW;
        half4v bl[4];
#pragma unroll
        for (int s4 = 0; s4 < 4; s4++) {
            half4v bv;
#pragma unroll
            for (int i = 0; i < 4; i++)
                bv[i] = (_Float16)LWp[(16 * s4 + krow + i) * 64 + 16 * w + col];
            bl[s4] = bv;
        }
        float lbv = wsf[OFF_LB + 16 * w + col];
        f32x4 acc = (f32x4){lbv, lbv, lbv, lbv};
#pragma unroll
        for (int s4 = 0; s4 < 4; s4++) {
            half4v a = *(const half4v*)&p2h[anode][(16 * s4 + krow) ^ asw];
            acc = __builtin_amdgcn_mfma_f32_16x16x16f16(a, bl[s4], acc, 0, 0, 0);
        }
        __syncthreads();   // zws fully dead; outf overlay now safe to write
#pragma unroll
        for (int i = 0; i < 4; i++) {
            int ndr = krow + i;
            outf[ndr][16 * w + col] = acc[i];
        }
    }
    __syncthreads();

    // ================= LayerNorm + ReLU + residual: 4 nodes per wave ===========
    for (int j = 0; j < 4; j++) {
        const int ndl = w * 4 + j;
        const int ng  = blockIdx.x * 16 + ndl;
        float a = outf[ndl][l];
        float s1 = a, sq = a * a;
#pragma unroll
        for (int o = 1; o < 64; o <<= 1) { s1 += __shfl_xor(s1, o); sq += __shfl_xor(sq, o); }
        float mu = s1 * (1.0f / 64.0f);
        float varl = sq * (1.0f / 64.0f) - mu * mu;
        float ln = (a - mu) * rsqrtf(varl + 1e-5f) * wsf[OFF_LG + l] + wsf[OFF_LBN + l];
        if (ng < Nn) {
            long idx = (long)ng * 64 + l;
            float res = rdin(ax, idx, mode) + fmaxf(ln, 0.f);
            if (mode == 0) ((u16*)outp)[idx] = f2bf(res);
            else           ((float*)outp)[idx] = res;
        }
    }
}

extern "C" void kernel_launch(void* const* d_in, const int* in_sizes, int n_in,
                              void* d_out, int out_size, void* d_ws, size_t ws_size,
                              hipStream_t stream) {
    const void* atom_x   = d_in[0];
    const void* bond_emb = d_in[1];
    const void* edge_w   = d_in[2];
    const void* edge_b   = d_in[3];
    const void* pre_w1   = d_in[4];
    const void* pre_b1   = d_in[5];
    const void* pre_w2   = d_in[6];
    const void* pre_b2   = d_in[7];
    const void* post_w1  = d_in[8];
    const void* post_b1  = d_in[9];
    const void* post_w2  = d_in[10];
    const void* post_b2  = d_in[11];
    const void* lin_w    = d_in[12];
    const void* lin_b    = d_in[13];
    const void* ln_g     = d_in[14];
    const void* ln_b     = d_in[15];
    const int* bond_x    = (const int*)d_in[16];
    const int* aei       = (const int*)d_in[17];

    int E  = in_sizes[16];
    int Nn = in_sizes[0] / 64;
    const int* srcp = aei;
    const int* dstp = aei + E;

    float* wsf = (float*)d_ws;
    int*   wsi = (int*)d_ws;

    size_t o = IB;
    int* modep = wsi + o; o += 16;
    int* cnt   = wsi + o; o += Nn;
    o = (o + 63) & ~(size_t)63;
    int* pk    = wsi + o; o += (size_t)Nn * MAXD;
    float* Yp  = (float*)(wsi + o); o += (size_t)Nn * 64;
    float* XWp = (float*)(wsi + o); o += (size_t)Nn * 64;
    // ws usage ~39 MB

    const int NIB  = 1600;
    const int SBLK = (E + 255) / 256;

    (void)hipMemsetAsync(cnt, 0, (size_t)Nn * sizeof(int), stream);
    k_prep<<<NIB + SBLK, 256, 0, stream>>>(dstp, srcp, bond_x,
                                           bond_emb, edge_w, edge_b,
                                           pre_w1, pre_b1, pre_w2, pre_b2,
                                           post_w1, post_b1, post_w2, post_b2,
                                           lin_w, lin_b, ln_g, ln_b,
                                           atom_x, wsf, Yp, XWp, cnt, pk, modep, Nn, E, NIB);
    dim3 gn((Nn + 15) / 16, 1, 1);
    k_node<<<gn, 256, 0, stream>>>(atom_x, Yp, XWp, pk, cnt, wsf, d_out, modep, Nn);
}

// Round 14
// 258.754 us; speedup vs baseline: 1.7517x; 1.0404x over previous
//
#include <hip/hip_runtime.h>
#include <cstdint>

typedef unsigned short u16;
typedef _Float16 half4v __attribute__((ext_vector_type(4)));
typedef float f32x4 __attribute__((ext_vector_type(4)));

#define AVG_LOG_F 1.4862356961977451f
#define MAXD 64

// ---- workspace float-unit offsets (weights region) ----
#define OFF_W2   3072   // pre_w2  fp32 [4][16][16]
#define OFF_PW1  4096   // post_w1 fp32 [4][256][16]
#define OFF_PW2  20480  // post_w2 fp32 [4][16][16]
#define OFF_LW   21504  // lin_w   fp32 [64][64]
#define OFF_PB1  25600
#define OFF_PB2  25664
#define OFF_QB1  25728
#define OFF_QB2  25792
#define OFF_LB   25856
#define OFF_LG   25920
#define OFF_LBN  25984
#define OFF_EWT  26128  // eWtab  fp32 [5][64]  (pb1 + ET.W1e, node-invariant)
#define IB       26448  // int region start (4B units)

__device__ __forceinline__ float bf2f(u16 u) {
    return __uint_as_float(((unsigned)u) << 16);
}
__device__ __forceinline__ u16 f2bf(float f) {
    unsigned u = __float_as_uint(f);
    u += 0x7fffu + ((u >> 16) & 1u);
    return (u16)(u >> 16);
}
__device__ __forceinline__ float rdin(const void* p, long j, int mode) {
    if (mode == 0) return bf2f(((const u16*)p)[j]);
    return ((const float*)p)[j];
}
template <int MODE>
__device__ __forceinline__ void load16c(const void* p, long base, float* o) {
    if (MODE == 0) {
        const u16* q = (const u16*)p + base;
        uint4 a = *(const uint4*)q;
        uint4 b = *(const uint4*)(q + 8);
        o[0]  = __uint_as_float(a.x << 16); o[1]  = __uint_as_float(a.x & 0xffff0000u);
        o[2]  = __uint_as_float(a.y << 16); o[3]  = __uint_as_float(a.y & 0xffff0000u);
        o[4]  = __uint_as_float(a.z << 16); o[5]  = __uint_as_float(a.z & 0xffff0000u);
        o[6]  = __uint_as_float(a.w << 16); o[7]  = __uint_as_float(a.w & 0xffff0000u);
        o[8]  = __uint_as_float(b.x << 16); o[9]  = __uint_as_float(b.x & 0xffff0000u);
        o[10] = __uint_as_float(b.y << 16); o[11] = __uint_as_float(b.y & 0xffff0000u);
        o[12] = __uint_as_float(b.z << 16); o[13] = __uint_as_float(b.z & 0xffff0000u);
        o[14] = __uint_as_float(b.w << 16); o[15] = __uint_as_float(b.w & 0xffff0000u);
    } else {
        const float* q = (const float*)p + base;
        float4 a = *(const float4*)q;
        float4 b = *(const float4*)(q + 4);
        float4 c = *(const float4*)(q + 8);
        float4 d = *(const float4*)(q + 12);
        o[0]=a.x; o[1]=a.y; o[2]=a.z; o[3]=a.w;
        o[4]=b.x; o[5]=b.y; o[6]=b.z; o[7]=b.w;
        o[8]=c.x; o[9]=c.y; o[10]=c.z; o[11]=c.w;
        o[12]=d.x; o[13]=d.y; o[14]=d.z; o[15]=d.w;
    }
}

// per-node precompute: Y[n][l] = x[n].W1_xj column,  XW[n][l] = x[n].W1_xi column
template <int MODE>
__device__ __forceinline__ void y_loop(const void* ax, const void* pre_w1, float* wsY, float* wsXW,
                                       int Nn, int wave, int nwaves, int l) {
    const int t = l >> 4, g = l & 15;
    float wxi[16], wxj[16];
#pragma unroll
    for (int f = 0; f < 16; f++) {
        wxi[f] = rdin(pre_w1, t * 768 + f * 16 + g, MODE);
        wxj[f] = rdin(pre_w1, t * 768 + (16 + f) * 16 + g, MODE);
    }
    for (int n = wave; n < Nn; n += nwaves) {
        float xj[16];
        load16c<MODE>(ax, (long)n * 64 + t * 16, xj);
        float accY = 0.f, accX = 0.f;
#pragma unroll
        for (int f = 0; f < 16; f++) {
            accY = fmaf(xj[f], wxj[f], accY);
            accX = fmaf(xj[f], wxi[f], accX);
        }
        wsY[(long)n * 64 + l]  = accY;
        wsXW[(long)n * 64 + l] = accX;
    }
}

// ---------------- 1: fused prep: weights->fp32, ET/eWtab, Y/XW precompute, edge scatter ----
__global__ __launch_bounds__(256) void k_prep(
    const int* __restrict__ dstp, const int* __restrict__ srcp, const int* __restrict__ bondp,
    const void* bond_emb, const void* edge_w, const void* edge_b,
    const void* pre_w1, const void* pre_b1, const void* pre_w2, const void* pre_b2,
    const void* post_w1, const void* post_b1, const void* post_w2, const void* post_b2,
    const void* lin_w, const void* lin_b, const void* ln_g, const void* ln_b,
    const void* ax, float* wsf, float* wsY, float* wsXW,
    int* __restrict__ cnt, int* __restrict__ pk, int* modep,
    int Nn, int E, int NIB)
{
    int tid = threadIdx.x;
    if ((int)blockIdx.x >= NIB) {            // ---- scatter part ----
        int e = ((int)blockIdx.x - NIB) * 256 + tid;
        if (e < E) {
            int d = dstp[e];
            int pos = atomicAdd(&cnt[d], 1);
            // pack (src*64)<<3 | bond  ->  k_node row offset = (v>>3)+l, bond = v&7
            if (pos < MAXD) pk[d * MAXD + pos] = (srcp[e] << 9) | (bondp[e] & 7);
        }
        return;
    }
    // ---- init part ----
    __shared__ int csh;
    __shared__ float ET[80];
    if (tid == 0) csh = 0;
    __syncthreads();
    {
        unsigned v = ((const unsigned*)ax)[tid];
        unsigned lo = v & 0xffffu;
        int ee = (int)((lo >> 7) & 0xff);
        int isbf = (lo == 0u) || (ee >= 110 && ee <= 140);
        atomicAdd(&csh, isbf);
    }
    __syncthreads();
    int mode = (csh >= 192) ? 0 : 1;

    int b = (int)blockIdx.x;
    int gt = b * 256 + tid;
    int gs = NIB * 256;
    if (b == 0 && tid == 0) modep[0] = mode;

    for (int j = gt; j < 1024; j += gs)  wsf[OFF_W2 + j]  = rdin(pre_w2, j, mode);
    for (int j = gt; j < 16384; j += gs) wsf[OFF_PW1 + j] = rdin(post_w1, j, mode);
    for (int j = gt; j < 1024; j += gs)  wsf[OFF_PW2 + j] = rdin(post_w2, j, mode);
    for (int j = gt; j < 4096; j += gs)  wsf[OFF_LW + j]  = rdin(lin_w, j, mode);
    for (int j = gt; j < 64; j += gs) {
        wsf[OFF_PB1 + j] = rdin(pre_b1, j, mode);
        wsf[OFF_PB2 + j] = rdin(pre_b2, j, mode);
        wsf[OFF_QB1 + j] = rdin(post_b1, j, mode);
        wsf[OFF_QB2 + j] = rdin(post_b2, j, mode);
        wsf[OFF_LB + j]  = rdin(lin_b, j, mode);
        wsf[OFF_LG + j]  = rdin(ln_g, j, mode);
        wsf[OFF_LBN + j] = rdin(ln_b, j, mode);
    }
    if (b == 0) {
        if (tid < 80) {
            int bb = tid >> 4, f = tid & 15;
            float acc = rdin(edge_b, f, mode);
            for (int k = 0; k < 64; k++)
                acc = fmaf(rdin(bond_emb, bb * 64 + k, mode), rdin(edge_w, k * 16 + f, mode), acc);
            ET[tid] = acc;
        }
        __syncthreads();
        for (int j = tid; j < 320; j += 256) {
            int bb = j >> 6, ll = j & 63, tt = ll >> 4, gg = ll & 15;
            float acc = rdin(pre_b1, tt * 16 + gg, mode);
#pragma unroll
            for (int f = 0; f < 16; f++)
                acc = fmaf(ET[bb * 16 + f], rdin(pre_w1, tt * 768 + (32 + f) * 16 + gg, mode), acc);
            wsf[OFF_EWT + j] = acc;
        }
    }
    int wave = gt >> 6;
    int nwaves = gs >> 6;
    int l = tid & 63;
    if (mode == 0) y_loop<0>(ax, pre_w1, wsY, wsXW, Nn, wave, nwaves, l);
    else           y_loop<1>(ax, pre_w1, wsY, wsXW, Nn, wave, nwaves, l);
}

// ---------------- 2: fused node kernel: all matmuls on matrix pipe, LDS overlays ---------
// 16 nodes/block, R10 structure + LDS overlays. SPILL FIX (R13 post-mortem): the edge
// inner loop's live set was ~82 regs > the allocator's 64-reg target -> ~38MB scratch
// traffic. Shrunk to ~54: gather split into two 8-edge halves (vs/yv 32->16 regs) and
// cinit[4] f32x4 (16 regs) replaced by 4 scalars rebuilt at the MFMA call.
__global__ __launch_bounds__(256, 4) void k_node(
    const void* __restrict__ ax, const float* __restrict__ Yp, const float* __restrict__ XWp,
    const int* __restrict__ pk, const int* __restrict__ cnt,
    const float* __restrict__ wsf, void* __restrict__ outp,
    const int* __restrict__ modep, int Nn)
{
    __shared__ _Float16 hbh[4][16][64];   // 8KB  per-wave edge-batch staging (swizzled)
    __shared__ float    zob[1280];        // 5KB  zws[4][5][64] (edge) ∪ outf[16][64] (final)
    __shared__ _Float16 xih[16][64];      // 2KB  x_i f16, swizzled rows
    __shared__ _Float16 aggh[5][16][64];  // 10KB stats f16; aggh[0]≡p1h, aggh[1]≡p2h overlay
    __shared__ float    scl1s[16], scl2s[16];

    const int w = threadIdx.x >> 6;
    const int l = threadIdx.x & 63;
    const int mode = modep[0];

    float* zws = &zob[w * 320];                        // [5][64] this wave (edge phase)
    float (*outf)[64] = (float(*)[64])&zob[0];         // [16][64] (after 2nd barrier)
    _Float16 (*p1h)[64] = (_Float16(*)[64])&aggh[0][0][0];
    _Float16 (*p2h)[64] = (_Float16(*)[64])&aggh[1][0][0];

    const int col  = l & 15;            // MFMA col / B col
    const int krow = (l >> 4) << 2;     // MFMA k-base / D row-base

    // ---- W2 B fragments + pb2 scalars for the edge-phase MFMAs ----
    half4v bfr[4];
    float pb2s[4];
#pragma unroll
    for (int tt = 0; tt < 4; tt++) {
        half4v bv;
#pragma unroll
        for (int i = 0; i < 4; i++)
            bv[i] = (_Float16)wsf[OFF_W2 + tt * 256 + (krow + i) * 16 + col];
        bfr[tt] = bv;
        pb2s[tt] = wsf[OFF_PB2 + tt * 16 + col];
    }

    const _Float16* hrow = &hbh[w][col][0];
    const int eswz = (l & 7) << 3;

    // ================= edge phase: 4 nodes per wave, sequential =================
    for (int j = 0; j < 4; j++) {
        const int ndl = w * 4 + j;
        const int ng  = blockIdx.x * 16 + ndl;
        const bool act = (ng < Nn);
        const int nn = act ? ng : 0;
        int deg = act ? cnt[nn] : 0;
        if (deg > MAXD) deg = MAXD;

        int   pkv = pk[nn * MAXD + l];
        float XWv = XWp[(long)nn * 64 + l];
        zws[0 * 64 + l] = XWv + wsf[OFF_EWT + 0 * 64 + l];
        zws[1 * 64 + l] = XWv + wsf[OFF_EWT + 1 * 64 + l];
        zws[2 * 64 + l] = XWv + wsf[OFF_EWT + 2 * 64 + l];
        zws[3 * 64 + l] = XWv + wsf[OFF_EWT + 3 * 64 + l];
        zws[4 * 64 + l] = XWv + wsf[OFF_EWT + 4 * 64 + l];
        const int nsw = (ndl & 7) << 3;
        xih[ndl][l ^ nsw] = (_Float16)rdin(ax, (long)nn * 64 + l, mode);

        float sA[4]  = {0.f, 0.f, 0.f, 0.f};
        float s2A[4] = {0.f, 0.f, 0.f, 0.f};
        float mnA[4] = {3.0e38f, 3.0e38f, 3.0e38f, 3.0e38f};
        float mxA[4] = {-3.0e38f, -3.0e38f, -3.0e38f, -3.0e38f};

        for (int kb = 0; kb < deg; kb += 16) {
            int B = deg - kb; if (B > 16) B = 16;
            // ---- gather + stage in two 8-edge halves (halves the live-reg set) ----
#pragma unroll
            for (int h = 0; h < 2; h++) {
                const int base = kb + h * 8;
                int Bh = deg - base; if (Bh > 8) Bh = 8; if (Bh < 0) Bh = 0;
                int vs[8]; float yv[8];
#pragma unroll
                for (int k = 0; k < 8; k++) {
                    if (k < Bh) {
                        vs[k] = __builtin_amdgcn_readlane(pkv, base + k);
                        yv[k] = Yp[(vs[k] >> 3) + l];
                    }
                }
#pragma unroll
                for (int k = 0; k < 8; k++) {
                    const int ke = h * 8 + k;
                    float hv = (k < Bh) ? fmaxf(yv[k] + zws[(vs[k] & 7) * 64 + l], 0.f) : 0.f;
                    hbh[w][ke][l ^ ((ke & 7) << 3)] = (_Float16)hv;
                }
            }
            if (B == 16) {
#pragma unroll
                for (int tt = 0; tt < 4; tt++) {
                    half4v a = *(const half4v*)&hrow[(tt * 16 + krow) ^ eswz];
                    f32x4 ci = (f32x4){pb2s[tt], pb2s[tt], pb2s[tt], pb2s[tt]};
                    f32x4 d = __builtin_amdgcn_mfma_f32_16x16x16f16(a, bfr[tt], ci, 0, 0, 0);
#pragma unroll
                    for (int i = 0; i < 4; i++) {
                        float m = d[i];
                        sA[tt] += m;
                        s2A[tt] = fmaf(m, m, s2A[tt]);
                        mnA[tt] = fminf(mnA[tt], m);
                        mxA[tt] = fmaxf(mxA[tt], m);
                    }
                }
            } else {
                const int ebase = kb + krow;
#pragma unroll
                for (int tt = 0; tt < 4; tt++) {
                    half4v a = *(const half4v*)&hrow[(tt * 16 + krow) ^ eswz];
                    f32x4 ci = (f32x4){pb2s[tt], pb2s[tt], pb2s[tt], pb2s[tt]};
                    f32x4 d = __builtin_amdgcn_mfma_f32_16x16x16f16(a, bfr[tt], ci, 0, 0, 0);
#pragma unroll
                    for (int i = 0; i < 4; i++) {
                        bool val = (ebase + i) < deg;
                        float m = d[i];
                        float mm = val ? m : 0.f;
                        sA[tt] += mm;
                        s2A[tt] = fmaf(mm, mm, s2A[tt]);
                        mnA[tt] = fminf(mnA[tt], val ? m : 3.0e38f);
                        mxA[tt] = fmaxf(mxA[tt], val ? m : -3.0e38f);
                    }
                }
            }
        }

        // reduce edge-row groups (lanes xor 16/32 share col), select own tower (t=l>>4)
#pragma unroll
        for (int tt = 0; tt < 4; tt++) {
            sA[tt]  += __shfl_xor(sA[tt], 16);  sA[tt]  += __shfl_xor(sA[tt], 32);
            s2A[tt] += __shfl_xor(s2A[tt], 16); s2A[tt] += __shfl_xor(s2A[tt], 32);
            mnA[tt] = fminf(mnA[tt], __shfl_xor(mnA[tt], 16));
            mnA[tt] = fminf(mnA[tt], __shfl_xor(mnA[tt], 32));
            mxA[tt] = fmaxf(mxA[tt], __shfl_xor(mxA[tt], 16));
            mxA[tt] = fmaxf(mxA[tt], __shfl_xor(mxA[tt], 32));
        }
        const int t = l >> 4;
        float s  = (t & 2) ? ((t & 1) ? sA[3]  : sA[2])  : ((t & 1) ? sA[1]  : sA[0]);
        float s2 = (t & 2) ? ((t & 1) ? s2A[3] : s2A[2]) : ((t & 1) ? s2A[1] : s2A[0]);
        float mn = (t & 2) ? ((t & 1) ? mnA[3] : mnA[2]) : ((t & 1) ? mnA[1] : mnA[0]);
        float mx = (t & 2) ? ((t & 1) ? mxA[3] : mxA[2]) : ((t & 1) ? mxA[1] : mxA[0]);

        if (deg == 0) { mn = 0.f; mx = 0.f; }
        float cf = (float)(deg > 0 ? deg : 1);
        float inv = 1.0f / cf;
        float mean = s * inv;
        float var = s2 * inv - mean * mean;
        float sd = sqrtf(fmaxf(var, 0.f) + 1e-5f);
        float ldv = logf(cf + 1.0f);

        aggh[0][ndl][l ^ nsw] = (_Float16)s;
        aggh[1][ndl][l ^ nsw] = (_Float16)mean;
        aggh[2][ndl][l ^ nsw] = (_Float16)mn;
        aggh[3][ndl][l ^ nsw] = (_Float16)mx;
        aggh[4][ndl][l ^ nsw] = (_Float16)sd;
        if (l == 0) {
            scl1s[ndl] = ldv * (1.0f / AVG_LOG_F);
            scl2s[ndl] = AVG_LOG_F / ldv;
        }
    }
    __syncthreads();

    // ================= layer 1: wave w = tower w, 16 MFMAs over K=256 ==========
    const int t = w;
    const float* PW1t = wsf + OFF_PW1 + t * 4096;
    const int anode = col;                 // A row = node
    const int asw   = (anode & 7) << 3;
    const int achan = t * 16 + krow;       // chan base within node row

    half4v b1[16];
#pragma unroll
    for (int jj = 0; jj < 16; jj++) {
        int rbase = (jj == 0) ? 0
                  : (jj <= 5)  ? 16  + (jj - 1)  * 16
                  : (jj <= 10) ? 96  + (jj - 6)  * 16
                  :              176 + (jj - 11) * 16;
        half4v bv;
#pragma unroll
        for (int i = 0; i < 4; i++)
            bv[i] = (_Float16)PW1t[(rbase + krow + i) * 16 + col];
        b1[jj] = bv;
    }

    f32x4 zero4 = (f32x4){0.f, 0.f, 0.f, 0.f};
    f32x4 q0, q1v, q2v;
    {
        half4v a = *(const half4v*)&xih[anode][achan ^ asw];
        q0 = __builtin_amdgcn_mfma_f32_16x16x16f16(a, b1[0], zero4, 0, 0, 0);
    }
#pragma unroll
    for (int a5 = 0; a5 < 5; a5++) {
        half4v a = *(const half4v*)&aggh[a5][anode][achan ^ asw];
        q0 = __builtin_amdgcn_mfma_f32_16x16x16f16(a, b1[1 + a5], q0, 0, 0, 0);
    }
    q1v = zero4; q2v = zero4;
#pragma unroll
    for (int a5 = 0; a5 < 5; a5++) {
        half4v a = *(const half4v*)&aggh[a5][anode][achan ^ asw];
        q1v = __builtin_amdgcn_mfma_f32_16x16x16f16(a, b1[6 + a5],  q1v, 0, 0, 0);
        q2v = __builtin_amdgcn_mfma_f32_16x16x16f16(a, b1[11 + a5], q2v, 0, 0, 0);
    }
    {
        float qb1v = wsf[OFF_QB1 + t * 16 + col];
#pragma unroll
        for (int i = 0; i < 4; i++) {
            int ndr = krow + i;            // D row = node
            float p1 = q0[i] + scl1s[ndr] * q1v[i] + scl2s[ndr] * q2v[i] + qb1v;
            p1 = fmaxf(p1, 0.f);
            p1h[ndr][(t * 16 + col) ^ ((ndr & 7) << 3)] = (_Float16)p1;
        }
    }
    // p1h (overlay aggh[0]) tower-t cols written AND read by wave t only -> no barrier

    // ================= layer 2: 1 MFMA per tower-wave ==========================
    {
        const float* PW2t = wsf + OFF_PW2 + t * 256;
        half4v b2;
#pragma unroll
        for (int i = 0; i < 4; i++)
            b2[i] = (_Float16)PW2t[(krow + i) * 16 + col];
        float qb2v = wsf[OFF_QB2 + t * 16 + col];
        f32x4 c2 = (f32x4){qb2v, qb2v, qb2v, qb2v};
        half4v a2 = *(const half4v*)&p1h[anode][achan ^ asw];
        f32x4 m2 = __builtin_amdgcn_mfma_f32_16x16x16f16(a2, b2, c2, 0, 0, 0);
#pragma unroll
        for (int i = 0; i < 4; i++) {
            int ndr = krow + i;
            p2h[ndr][(t * 16 + col) ^ ((ndr & 7) << 3)] = (_Float16)m2[i];
        }
    }
    __syncthreads();

    // ================= final 64x64 linear: wave w -> out cols [16w,16w+16) =====
    {
        const float* LWp = wsf + OFF_LW;
        half4v bl[4];
#pragma unroll
        for (int s4 = 0; s4 < 4; s4++) {
            half4v bv;
#pragma unroll
            for (int i = 0; i < 4; i++)
                bv[i] = (_Float16)LWp[(16 * s4 + krow + i) * 64 + 16 * w + col];
            bl[s4] = bv;
        }
        float lbv = wsf[OFF_LB + 16 * w + col];
        f32x4 acc = (f32x4){lbv, lbv, lbv, lbv};
#pragma unroll
        for (int s4 = 0; s4 < 4; s4++) {
            half4v a = *(const half4v*)&p2h[anode][(16 * s4 + krow) ^ asw];
            acc = __builtin_amdgcn_mfma_f32_16x16x16f16(a, bl[s4], acc, 0, 0, 0);
        }
        __syncthreads();   // zws fully dead; outf overlay now safe to write
#pragma unroll
        for (int i = 0; i < 4; i++) {
            int ndr = krow + i;
            outf[ndr][16 * w + col] = acc[i];
        }
    }
    __syncthreads();

    // ================= LayerNorm + ReLU + residual: 4 nodes per wave ===========
    for (int j = 0; j < 4; j++) {
        const int ndl = w * 4 + j;
        const int ng  = blockIdx.x * 16 + ndl;
        float a = outf[ndl][l];
        float s1 = a, sq = a * a;
#pragma unroll
        for (int o = 1; o < 64; o <<= 1) { s1 += __shfl_xor(s1, o); sq += __shfl_xor(sq, o); }
        float mu = s1 * (1.0f / 64.0f);
        float varl = sq * (1.0f / 64.0f) - mu * mu;
        float ln = (a - mu) * rsqrtf(varl + 1e-5f) * wsf[OFF_LG + l] + wsf[OFF_LBN + l];
        if (ng < Nn) {
            long idx = (long)ng * 64 + l;
            float res = rdin(ax, idx, mode) + fmaxf(ln, 0.f);
            if (mode == 0) ((u16*)outp)[idx] = f2bf(res);
            else           ((float*)outp)[idx] = res;
        }
    }
}

extern "C" void kernel_launch(void* const* d_in, const int* in_sizes, int n_in,
                              void* d_out, int out_size, void* d_ws, size_t ws_size,
                              hipStream_t stream) {
    const void* atom_x   = d_in[0];
    const void* bond_emb = d_in[1];
    const void* edge_w   = d_in[2];
    const void* edge_b   = d_in[3];
    const void* pre_w1   = d_in[4];
    const void* pre_b1   = d_in[5];
    const void* pre_w2   = d_in[6];
    const void* pre_b2   = d_in[7];
    const void* post_w1  = d_in[8];
    const void* post_b1  = d_in[9];
    const void* post_w2  = d_in[10];
    const void* post_b2  = d_in[11];
    const void* lin_w    = d_in[12];
    const void* lin_b    = d_in[13];
    const void* ln_g     = d_in[14];
    const void* ln_b     = d_in[15];
    const int* bond_x    = (const int*)d_in[16];
    const int* aei       = (const int*)d_in[17];

    int E  = in_sizes[16];
    int Nn = in_sizes[0] / 64;
    const int* srcp = aei;
    const int* dstp = aei + E;

    float* wsf = (float*)d_ws;
    int*   wsi = (int*)d_ws;

    size_t o = IB;
    int* modep = wsi + o; o += 16;
    int* cnt   = wsi + o; o += Nn;
    o = (o + 63) & ~(size_t)63;
    int* pk    = wsi + o; o += (size_t)Nn * MAXD;
    float* Yp  = (float*)(wsi + o); o += (size_t)Nn * 64;
    float* XWp = (float*)(wsi + o); o += (size_t)Nn * 64;
    // ws usage ~39 MB

    const int NIB  = 1600;
    const int SBLK = (E + 255) / 256;

    (void)hipMemsetAsync(cnt, 0, (size_t)Nn * sizeof(int), stream);
    k_prep<<<NIB + SBLK, 256, 0, stream>>>(dstp, srcp, bond_x,
                                           bond_emb, edge_w, edge_b,
                                           pre_w1, pre_b1, pre_w2, pre_b2,
                                           post_w1, post_b1, post_w2, post_b2,
                                           lin_w, lin_b, ln_g, ln_b,
                                           atom_x, wsf, Yp, XWp, cnt, pk, modep, Nn, E, NIB);
    dim3 gn((Nn + 15) / 16, 1, 1);
    k_node<<<gn, 256, 0, stream>>>(atom_x, Yp, XWp, pk, cnt, wsf, d_out, modep, Nn);
}